// Round 2
// baseline (3243.171 us; speedup 1.0000x reference)
//
#include <hip/hip_runtime.h>
#include <hip/hip_bf16.h>
#include <math.h>

#define B_  2048
#define L_  128
#define D_  100
#define H_  50
#define NE  1024
#define NC  1024
#define NP  (NE*NC)

__device__ __forceinline__ float sigf(float x) { return 1.f / (1.f + __expf(-x)); }

// ---------------- kernel 1: flatnonzero index lists ----------------
__global__ __launch_bounds__(256) void k_build_idx(const int* __restrict__ emo,
                                                   const int* __restrict__ cau,
                                                   int* __restrict__ emo_idx,
                                                   int* __restrict__ cau_idx) {
  __shared__ int pe[256], pc[256];
  int tid = threadIdx.x;
  int ce = 0, cc = 0;
  int base = tid * 8;
  for (int r = 0; r < 8; r++) { ce += (emo[base + r] != 0); cc += (cau[base + r] != 0); }
  pe[tid] = ce; pc[tid] = cc;
  __syncthreads();
  if (tid == 0) {
    int re = 0, rc = 0;
    for (int i = 0; i < 256; i++) {
      int t = pe[i]; pe[i] = re; re += t;
      t = pc[i]; pc[i] = rc; rc += t;
    }
  }
  __syncthreads();
  int oe = pe[tid], oc = pc[tid];
  for (int r = 0; r < 8; r++) {
    int idx = base + r;
    if (emo[idx] != 0) emo_idx[oe++] = idx;
    if (cau[idx] != 0) cau_idx[oc++] = idx;
  }
}

// ---------------- kernel 2: masked forward LSTM (8 batches / block) ----------------
__global__ __launch_bounds__(256) void k_lstm_fwd(const float* __restrict__ x,
                                                  const int* __restrict__ lens,
                                                  const float* __restrict__ Wih,
                                                  const float* __restrict__ Whh,
                                                  const float* __restrict__ bih,
                                                  const float* __restrict__ bhh,
                                                  float* __restrict__ U) {
  __shared__ float Wih_l[100][200];   // [i][j] transposed for lane-consecutive j
  __shared__ float Whh_l[50][200];
  __shared__ float bias_l[200];
  __shared__ float xs[8][100];
  __shared__ float hb[8][50];
  __shared__ float gb[8][200];
  __shared__ int len_l[8];
  int tid = threadIdx.x;
  int b0 = blockIdx.x * 8;
  for (int id = tid; id < 20000; id += 256) { int j = id / 100, i = id % 100; Wih_l[i][j] = Wih[id]; }
  for (int id = tid; id < 10000; id += 256) { int j = id / 50,  i = id % 50;  Whh_l[i][j] = Whh[id]; }
  if (tid < 200) bias_l[tid] = bih[tid] + bhh[tid];
  if (tid < 8) len_l[tid] = lens[b0 + tid];
  int uk = tid % 50, ub = tid / 50;     // update-phase mapping (tid<200)
  if (tid < 200) { hb[ub][uk] = 0.f; hb[ub + 4][uk] = 0.f; }
  __syncthreads();
  int maxlen = 1;
  for (int b = 0; b < 8; b++) maxlen = max(maxlen, len_l[b]);
  float c0 = 0.f, c1 = 0.f;             // persistent cell state (this thread's 2 units)
  int j = tid;                          // gate index (tid<200)
  for (int t = 0; t < maxlen; t++) {
    for (int id = tid; id < 800; id += 256) {
      int b = id / 100, i = id % 100;
      xs[b][i] = x[(b0 + b) * (L_ * D_) + t * D_ + i];
    }
    __syncthreads();
    if (j < 200) {
      float acc[8];
      float bj = bias_l[j];
      #pragma unroll
      for (int b = 0; b < 8; b++) acc[b] = bj;
      #pragma unroll 2
      for (int k = 0; k < 100; k++) {
        float w = Wih_l[k][j];
        #pragma unroll
        for (int b = 0; b < 8; b++) acc[b] = fmaf(w, xs[b][k], acc[b]);
      }
      #pragma unroll 2
      for (int k = 0; k < 50; k++) {
        float w = Whh_l[k][j];
        #pragma unroll
        for (int b = 0; b < 8; b++) acc[b] = fmaf(w, hb[b][k], acc[b]);
      }
      #pragma unroll
      for (int b = 0; b < 8; b++) gb[b][j] = acc[b];
    }
    __syncthreads();
    if (tid < 200) {
      if (t < len_l[ub]) {
        float gi = gb[ub][uk], gf = gb[ub][50 + uk], gg = gb[ub][100 + uk], go = gb[ub][150 + uk];
        float cn = sigf(gf) * c0 + sigf(gi) * tanhf(gg);
        c0 = cn;
        hb[ub][uk] = sigf(go) * tanhf(cn);
      }
      int b2 = ub + 4;
      if (t < len_l[b2]) {
        float gi = gb[b2][uk], gf = gb[b2][50 + uk], gg = gb[b2][100 + uk], go = gb[b2][150 + uk];
        float cn = sigf(gf) * c1 + sigf(gi) * tanhf(gg);
        c1 = cn;
        hb[b2][uk] = sigf(go) * tanhf(cn);
      }
    }
    __syncthreads();
  }
  if (tid < 200) {
    U[(b0 + ub) * 100 + uk]     = hb[ub][uk];
    U[(b0 + ub + 4) * 100 + uk] = hb[ub + 4][uk];
  }
}

// ---------------- kernel 3: backward single cell (h0=c0=0 -> W_hh_b unused) ----------------
__global__ __launch_bounds__(256) void k_lstm_bwd(const float* __restrict__ x,
                                                  const int* __restrict__ lens,
                                                  const float* __restrict__ Wih,
                                                  const float* __restrict__ bih,
                                                  const float* __restrict__ bhh,
                                                  float* __restrict__ U) {
  __shared__ float W_l[100][200];
  __shared__ float bias_l[200];
  __shared__ float xs[8][100];
  __shared__ float gb[8][200];
  __shared__ int len_l[8];
  int tid = threadIdx.x;
  int b0 = blockIdx.x * 8;
  for (int id = tid; id < 20000; id += 256) { int j = id / 100, i = id % 100; W_l[i][j] = Wih[id]; }
  if (tid < 200) bias_l[tid] = bih[tid] + bhh[tid];
  if (tid < 8) len_l[tid] = lens[b0 + tid];
  __syncthreads();
  for (int id = tid; id < 800; id += 256) {
    int b = id / 100, i = id % 100;
    int t = len_l[b] - 1;
    xs[b][i] = x[(b0 + b) * (L_ * D_) + t * D_ + i];
  }
  __syncthreads();
  int j = tid;
  if (j < 200) {
    float acc[8];
    float bj = bias_l[j];
    #pragma unroll
    for (int b = 0; b < 8; b++) acc[b] = bj;
    #pragma unroll 2
    for (int k = 0; k < 100; k++) {
      float w = W_l[k][j];
      #pragma unroll
      for (int b = 0; b < 8; b++) acc[b] = fmaf(w, xs[b][k], acc[b]);
    }
    #pragma unroll
    for (int b = 0; b < 8; b++) gb[b][j] = acc[b];
  }
  __syncthreads();
  if (tid < 200) {
    int uk = tid % 50, ub = tid / 50;
    #pragma unroll
    for (int s = 0; s < 2; s++) {
      int b = ub + 4 * s;
      float gi = gb[b][uk], gg = gb[b][100 + uk], go = gb[b][150 + uk];
      float cn = sigf(gi) * tanhf(gg);
      U[(b0 + b) * 100 + 50 + uk] = sigf(go) * tanhf(cn);
    }
  }
}

// ---------------- kernel 4: A = E@W1^T, B = C@W2^T, row norms ----------------
__global__ __launch_bounds__(128) void k_prep(const float* __restrict__ U,
                                              const int* __restrict__ emo_idx,
                                              const int* __restrict__ cau_idx,
                                              const float* __restrict__ W3w,
                                              float* __restrict__ A,
                                              float* __restrict__ Bc,
                                              float* __restrict__ En,
                                              float* __restrict__ Cn) {
  __shared__ float u[100];
  int bid = blockIdx.x;
  int tid = threadIdx.x;
  bool is_e = bid < NE;
  int i = is_e ? bid : bid - NE;
  int row = is_e ? emo_idx[i] : cau_idx[i];
  if (tid < 100) u[tid] = U[row * 100 + tid];
  __syncthreads();
  if (tid < 100) {
    int off = is_e ? 0 : 100;
    float acc = 0.f;
    const float* wrow = W3w + tid * 301 + off;
    #pragma unroll 4
    for (int k = 0; k < 100; k++) acc = fmaf(u[k], wrow[k], acc);
    if (is_e) A[i * 100 + tid] = acc; else Bc[i * 100 + tid] = acc;
  }
  if (tid < 64) {
    float v = u[tid] * u[tid];
    if (tid < 36) v += u[tid + 64] * u[tid + 64];
    for (int o = 32; o > 0; o >>= 1) v += __shfl_down(v, o);
    if (tid == 0) { if (is_e) En[i] = v; else Cn[i] = v; }
  }
}

// ---------------- kernel 5: fused pair bilinear + sigmoid + cls + log_softmax + labels ----
__global__ __launch_bounds__(256) void k_pair(const float* __restrict__ U,
                                              const int* __restrict__ emo_idx,
                                              const int* __restrict__ cau_idx,
                                              const float* __restrict__ A,
                                              const float* __restrict__ Bc,
                                              const float* __restrict__ En,
                                              const float* __restrict__ Cn,
                                              const float* __restrict__ W3w,
                                              const float* __restrict__ W3b,
                                              const float* __restrict__ clsw,
                                              const float* __restrict__ clsb,
                                              const int* __restrict__ label3,
                                              float* __restrict__ out) {
  __shared__ __align__(16) float M_l[112 * 104];  // M[d][k] = W4[d,k]*E[k]; row100 = E (dot smuggle)
  __shared__ __align__(16) float C_l[100 * 64];   // C[k][c]
  __shared__ float h_l[64 * 101];
  __shared__ float E_l[100];
  __shared__ float A_l[112], wd_l[112], b3_l[112];
  __shared__ float clsw_l[200], clsb_l[2];
  __shared__ float dist_l[64], Cn_l[64];
  __shared__ int crow_l[64], lbl_l[3];
  __shared__ float En_s;

  int tid = threadIdx.x;
  int e  = blockIdx.x >> 4;
  int c0 = (blockIdx.x & 15) * 64;
  int erow = emo_idx[e];

  if (tid < 100) E_l[tid] = U[erow * 100 + tid];
  if (tid < 112) {
    A_l[tid]  = (tid < 100) ? A[e * 100 + tid] : 0.f;
    wd_l[tid] = (tid < 100) ? W3w[tid * 301 + 200] : 0.f;
    b3_l[tid] = (tid < 100) ? W3b[tid] : 0.f;
  }
  if (tid < 200) clsw_l[tid] = clsw[tid];
  if (tid < 2) clsb_l[tid] = clsb[tid];
  if (tid < 64) { crow_l[tid] = cau_idx[c0 + tid]; Cn_l[tid] = Cn[c0 + tid]; }
  if (tid < 3) lbl_l[tid] = label3[e * 3 + tid];
  if (tid == 0) En_s = En[e];
  __syncthreads();
  for (int id = tid; id < 6400; id += 256) {
    int cc = id / 100, k = id % 100;
    C_l[k * 64 + cc] = U[crow_l[cc] * 100 + k];
  }
  for (int id = tid; id < 11200; id += 256) {
    int d = id / 100, k = id % 100;
    float v;
    if (d < 100)       v = W3w[d * 301 + 201 + k] * E_l[k];
    else if (d == 100) v = E_l[k];
    else               v = 0.f;
    M_l[d * 104 + k] = v;
  }
  __syncthreads();

  int ct = tid & 15, dt = tid >> 4;     // 16 c-threads x 16 d-threads; tile 4c x 7d
  float acc[4][7];
  #pragma unroll
  for (int a = 0; a < 4; a++)
    #pragma unroll
    for (int s = 0; s < 7; s++) acc[a][s] = 0.f;

  const float* Cb = &C_l[ct * 4];
  const float* Mb = &M_l[dt * 7 * 104];
  for (int k4 = 0; k4 < 100; k4 += 4) {
    float cv[4][4];
    float mv[7][4];
    #pragma unroll
    for (int i = 0; i < 4; i++) *(float4*)&cv[i][0] = *(const float4*)&Cb[(k4 + i) * 64];
    #pragma unroll
    for (int s = 0; s < 7; s++) *(float4*)&mv[s][0] = *(const float4*)&Mb[s * 104 + k4];
    #pragma unroll
    for (int i = 0; i < 4; i++) {
      #pragma unroll
      for (int s = 0; s < 7; s++) {
        float m = mv[s][i];
        #pragma unroll
        for (int a = 0; a < 4; a++) acc[a][s] = fmaf(cv[i][a], m, acc[a][s]);
      }
    }
  }

  if (dt == 14) {                       // owns d=98..104; s=2 -> d=100 = E.C dot
    #pragma unroll
    for (int a = 0; a < 4; a++) {
      int c = ct * 4 + a;
      float dot = acc[a][2];
      float d2 = En_s + Cn_l[c] - 2.f * dot;
      dist_l[c] = sqrtf(fmaxf(d2, 0.f));
    }
  }
  __syncthreads();

  #pragma unroll
  for (int s = 0; s < 7; s++) {
    int d = dt * 7 + s;
    if (d < 100) {
      float ad = A_l[d], wdd = wd_l[d], bd = b3_l[d];
      #pragma unroll
      for (int a = 0; a < 4; a++) {
        int c = ct * 4 + a;
        float z = acc[a][s] + ad + Bc[(c0 + c) * 100 + d] + dist_l[c] * wdd + bd;
        h_l[c * 101 + d] = 1.f / (1.f + __expf(-z));
      }
    }
  }
  __syncthreads();

  if (tid < 64) {
    int c = tid;
    float l0 = clsb_l[0], l1 = clsb_l[1];
    #pragma unroll 4
    for (int d = 0; d < 100; d++) {
      float hv = h_l[c * 101 + d];
      l0 = fmaf(hv, clsw_l[d], l0);
      l1 = fmaf(hv, clsw_l[100 + d], l1);
    }
    float mx = fmaxf(l0, l1);
    float lse = mx + __logf(__expf(l0 - mx) + __expf(l1 - mx));
    int pair = e * 1024 + c0 + c;
    out[pair * 2]     = l0 - lse;
    out[pair * 2 + 1] = l1 - lse;
    int cidx = c0 + c;
    float lab = (lbl_l[0] == cidx || lbl_l[1] == cidx || lbl_l[2] == cidx) ? 1.f : 0.f;
    out[2 * NP + pair] = lab;
  }
}

extern "C" void kernel_launch(void* const* d_in, const int* in_sizes, int n_in,
                              void* d_out, int out_size, void* d_ws, size_t ws_size,
                              hipStream_t stream) {
  const float* x     = (const float*)d_in[0];
  const int*   lens  = (const int*)d_in[1];
  const int*   emo   = (const int*)d_in[2];
  const int*   cau   = (const int*)d_in[3];
  const int*   lbl3  = (const int*)d_in[4];
  const float* Wih_f = (const float*)d_in[5];
  const float* Whh_f = (const float*)d_in[6];
  const float* bih_f = (const float*)d_in[7];
  const float* bhh_f = (const float*)d_in[8];
  const float* Wih_b = (const float*)d_in[9];
  // d_in[10] = W_hh_b unused: h0 = 0
  const float* bih_b = (const float*)d_in[11];
  const float* bhh_b = (const float*)d_in[12];
  const float* W3w   = (const float*)d_in[13];
  const float* W3b   = (const float*)d_in[14];
  const float* clsw  = (const float*)d_in[15];
  const float* clsb  = (const float*)d_in[16];
  float* out = (float*)d_out;

  char* ws = (char*)d_ws;
  float* U       = (float*)ws;              // 2048*100 f   = 819200 B
  int*   emo_idx = (int*)(ws + 819200);     // 1024 i
  int*   cau_idx = (int*)(ws + 823296);     // 1024 i
  float* A       = (float*)(ws + 827392);   // 1024*100 f
  float* Bc      = (float*)(ws + 1236992);  // 1024*100 f
  float* En      = (float*)(ws + 1646592);  // 1024 f
  float* Cn      = (float*)(ws + 1650688);  // 1024 f

  hipLaunchKernelGGL(k_build_idx, dim3(1), dim3(256), 0, stream, emo, cau, emo_idx, cau_idx);
  hipLaunchKernelGGL(k_lstm_fwd, dim3(256), dim3(256), 0, stream,
                     x, lens, Wih_f, Whh_f, bih_f, bhh_f, U);
  hipLaunchKernelGGL(k_lstm_bwd, dim3(256), dim3(256), 0, stream,
                     x, lens, Wih_b, bih_b, bhh_b, U);
  hipLaunchKernelGGL(k_prep, dim3(2048), dim3(128), 0, stream,
                     U, emo_idx, cau_idx, W3w, A, Bc, En, Cn);
  hipLaunchKernelGGL(k_pair, dim3(16384), dim3(256), 0, stream,
                     U, emo_idx, cau_idx, A, Bc, En, Cn, W3w, W3b, clsw, clsb, lbl3, out);
}

// Round 3
// 2185.402 us; speedup vs baseline: 1.4840x; 1.4840x over previous
//
#include <hip/hip_runtime.h>
#include <hip/hip_bf16.h>
#include <math.h>

#define B_  2048
#define L_  128
#define D_  100
#define H_  50
#define NE  1024
#define NC  1024
#define NP  (NE*NC)

typedef __attribute__((ext_vector_type(8))) short short8v;
typedef __attribute__((ext_vector_type(4))) float f32x4;

__device__ __forceinline__ float sigf(float x) { return 1.f / (1.f + __expf(-x)); }

__device__ __forceinline__ unsigned short f2bf(float f) {
  __hip_bfloat16 h = __float2bfloat16(f);
  unsigned short u;
  __builtin_memcpy(&u, &h, 2);
  return u;
}

// ---------------- kernel 1: flatnonzero index lists ----------------
__global__ __launch_bounds__(256) void k_build_idx(const int* __restrict__ emo,
                                                   const int* __restrict__ cau,
                                                   int* __restrict__ emo_idx,
                                                   int* __restrict__ cau_idx) {
  __shared__ int pe[256], pc[256];
  int tid = threadIdx.x;
  int ce = 0, cc = 0;
  int base = tid * 8;
  for (int r = 0; r < 8; r++) { ce += (emo[base + r] != 0); cc += (cau[base + r] != 0); }
  pe[tid] = ce; pc[tid] = cc;
  __syncthreads();
  if (tid == 0) {
    int re = 0, rc = 0;
    for (int i = 0; i < 256; i++) {
      int t = pe[i]; pe[i] = re; re += t;
      t = pc[i]; pc[i] = rc; rc += t;
    }
  }
  __syncthreads();
  int oe = pe[tid], oc = pc[tid];
  for (int r = 0; r < 8; r++) {
    int idx = base + r;
    if (emo[idx] != 0) emo_idx[oe++] = idx;
    if (cau[idx] != 0) cau_idx[oc++] = idx;
  }
}

// ---------------- kernel 2: masked forward LSTM ----------------
// x reads: wave-uniform global loads (-> s_load, SMEM pipe, no LDS).
// W reads: [k][j] lane-consecutive b32 (conflict-free).
// h reads: float4 LDS broadcasts.
__global__ __launch_bounds__(256) void k_lstm_fwd(const float* __restrict__ x,
                                                  const int* __restrict__ lens,
                                                  const float* __restrict__ Wih,
                                                  const float* __restrict__ Whh,
                                                  const float* __restrict__ bih,
                                                  const float* __restrict__ bhh,
                                                  float* __restrict__ U) {
  __shared__ float Wih_l[100][200];              // [k][j]
  __shared__ float Whh_l[52][200];               // rows 50,51 zero-padded
  __shared__ float bias_l[200];
  __shared__ __align__(16) float hb[8][52];      // cols 50,51 stay zero
  __shared__ float gb[8][200];
  __shared__ int len_l[8];
  int tid = threadIdx.x;
  int b0 = blockIdx.x * 8;
  for (int id = tid; id < 20000; id += 256) { int j = id / 100, k = id % 100; Wih_l[k][j] = Wih[id]; }
  for (int id = tid; id < 10400; id += 256) { int k = id / 200, j = id % 200; Whh_l[k][j] = (k < 50) ? Whh[j * 50 + k] : 0.f; }
  if (tid < 200) bias_l[tid] = bih[tid] + bhh[tid];
  if (tid < 8) len_l[tid] = lens[b0 + tid];
  for (int id = tid; id < 416; id += 256) { hb[id / 52][id % 52] = 0.f; }
  __syncthreads();
  int maxlen = 1;
  #pragma unroll
  for (int b = 0; b < 8; b++) maxlen = max(maxlen, len_l[b]);
  int jj = tid < 200 ? tid : 199;                // branchless: keep x loads uniform
  int uk = tid % 50, ub = tid / 50;
  float c0 = 0.f, c1 = 0.f;
  const float* xbase = x + (size_t)b0 * (L_ * D_);
  for (int t = 0; t < maxlen; t++) {
    float acc[8];
    float bj = bias_l[jj];
    #pragma unroll
    for (int b = 0; b < 8; b++) acc[b] = bj;
    const float* xt = xbase + t * D_;
    for (int k4 = 0; k4 < 25; k4++) {
      float w0 = Wih_l[k4 * 4 + 0][jj], w1 = Wih_l[k4 * 4 + 1][jj];
      float w2 = Wih_l[k4 * 4 + 2][jj], w3 = Wih_l[k4 * 4 + 3][jj];
      #pragma unroll
      for (int b = 0; b < 8; b++) {
        float4 xv = *(const float4*)(xt + b * (L_ * D_) + k4 * 4);  // uniform -> s_load
        acc[b] = fmaf(w0, xv.x, fmaf(w1, xv.y, fmaf(w2, xv.z, fmaf(w3, xv.w, acc[b]))));
      }
    }
    for (int k4 = 0; k4 < 13; k4++) {
      float w0 = Whh_l[k4 * 4 + 0][jj], w1 = Whh_l[k4 * 4 + 1][jj];
      float w2 = Whh_l[k4 * 4 + 2][jj], w3 = Whh_l[k4 * 4 + 3][jj];
      #pragma unroll
      for (int b = 0; b < 8; b++) {
        float4 hv = *(const float4*)&hb[b][k4 * 4];
        acc[b] = fmaf(w0, hv.x, fmaf(w1, hv.y, fmaf(w2, hv.z, fmaf(w3, hv.w, acc[b]))));
      }
    }
    if (tid < 200) {
      #pragma unroll
      for (int b = 0; b < 8; b++) gb[b][tid] = acc[b];
    }
    __syncthreads();
    if (tid < 200) {
      if (t < len_l[ub]) {
        float gi = gb[ub][uk], gf = gb[ub][50 + uk], gg = gb[ub][100 + uk], go = gb[ub][150 + uk];
        float cn = sigf(gf) * c0 + sigf(gi) * tanhf(gg);
        c0 = cn;
        hb[ub][uk] = sigf(go) * tanhf(cn);
      }
      int b2 = ub + 4;
      if (t < len_l[b2]) {
        float gi = gb[b2][uk], gf = gb[b2][50 + uk], gg = gb[b2][100 + uk], go = gb[b2][150 + uk];
        float cn = sigf(gf) * c1 + sigf(gi) * tanhf(gg);
        c1 = cn;
        hb[b2][uk] = sigf(go) * tanhf(cn);
      }
    }
    __syncthreads();
  }
  if (tid < 200) {
    U[(b0 + ub) * 100 + uk]     = hb[ub][uk];
    U[(b0 + ub + 4) * 100 + uk] = hb[ub + 4][uk];
  }
}

// ---------------- kernel 3: backward single cell (h0=c0=0 -> W_hh_b unused) ----------------
__global__ __launch_bounds__(256) void k_lstm_bwd(const float* __restrict__ x,
                                                  const int* __restrict__ lens,
                                                  const float* __restrict__ Wih,
                                                  const float* __restrict__ bih,
                                                  const float* __restrict__ bhh,
                                                  float* __restrict__ U) {
  __shared__ float W_l[100][200];
  __shared__ float bias_l[200];
  __shared__ float xs[8][100];
  __shared__ float gb[8][200];
  __shared__ int len_l[8];
  int tid = threadIdx.x;
  int b0 = blockIdx.x * 8;
  for (int id = tid; id < 20000; id += 256) { int j = id / 100, i = id % 100; W_l[i][j] = Wih[id]; }
  if (tid < 200) bias_l[tid] = bih[tid] + bhh[tid];
  if (tid < 8) len_l[tid] = lens[b0 + tid];
  __syncthreads();
  for (int id = tid; id < 800; id += 256) {
    int b = id / 100, i = id % 100;
    int t = len_l[b] - 1;
    xs[b][i] = x[(b0 + b) * (L_ * D_) + t * D_ + i];
  }
  __syncthreads();
  int j = tid;
  if (j < 200) {
    float acc[8];
    float bj = bias_l[j];
    #pragma unroll
    for (int b = 0; b < 8; b++) acc[b] = bj;
    #pragma unroll 2
    for (int k = 0; k < 100; k++) {
      float w = W_l[k][j];
      #pragma unroll
      for (int b = 0; b < 8; b++) acc[b] = fmaf(w, xs[b][k], acc[b]);
    }
    #pragma unroll
    for (int b = 0; b < 8; b++) gb[b][j] = acc[b];
  }
  __syncthreads();
  if (tid < 200) {
    int uk = tid % 50, ub = tid / 50;
    #pragma unroll
    for (int s = 0; s < 2; s++) {
      int b = ub + 4 * s;
      float gi = gb[b][uk], gg = gb[b][100 + uk], go = gb[b][150 + uk];
      float cn = sigf(gi) * tanhf(gg);
      U[(b0 + b) * 100 + 50 + uk] = sigf(go) * tanhf(cn);
    }
  }
}

// ---------------- kernel 4: A = E@W1^T + row norms (Bc folded into MFMA) --------
__global__ __launch_bounds__(128) void k_prep(const float* __restrict__ U,
                                              const int* __restrict__ emo_idx,
                                              const int* __restrict__ cau_idx,
                                              const float* __restrict__ W3w,
                                              float* __restrict__ A,
                                              float* __restrict__ En,
                                              float* __restrict__ Cn) {
  __shared__ float u[100];
  int bid = blockIdx.x;
  int tid = threadIdx.x;
  bool is_e = bid < NE;
  int i = is_e ? bid : bid - NE;
  int row = is_e ? emo_idx[i] : cau_idx[i];
  if (tid < 100) u[tid] = U[row * 100 + tid];
  __syncthreads();
  if (is_e && tid < 100) {
    float acc = 0.f;
    const float* wrow = W3w + tid * 301;
    #pragma unroll 4
    for (int k = 0; k < 100; k++) acc = fmaf(u[k], wrow[k], acc);
    A[i * 100 + tid] = acc;
  }
  if (tid < 64) {
    float v = u[tid] * u[tid];
    if (tid < 36) v += u[tid + 64] * u[tid + 64];
    for (int o = 32; o > 0; o >>= 1) v += __shfl_down(v, o);
    if (tid == 0) { if (is_e) En[i] = v; else Cn[i] = v; }
  }
}

// ---------------- kernel 5: pair via bf16 MFMA ----------------
// P[c][d] = sum_k C[c,k]*(W4[d,k]*E[k] + W2[d,k])   (Bc folded in)
// col d=100 of B = E  ->  P[c][100] = E.C (dist smuggle)
// z = P + (A[e,d]+b3[d]) + dist[c]*wd[d];  h=sigmoid;  cls + log_softmax in-register.
__global__ __launch_bounds__(512) void k_pair(const float* __restrict__ U,
                                              const int* __restrict__ emo_idx,
                                              const int* __restrict__ cau_idx,
                                              const float* __restrict__ A,
                                              const float* __restrict__ En,
                                              const float* __restrict__ Cn,
                                              const float* __restrict__ W3w,
                                              const float* __restrict__ W3b,
                                              const float* __restrict__ clsw,
                                              const float* __restrict__ clsb,
                                              const int* __restrict__ label3,
                                              float* __restrict__ out) {
  // 256B rows (128 bf16), 16B slots swizzled: slot ^= row&7  -> conflict-free b128
  __shared__ __align__(16) unsigned short Abf[128 * 128];   // C rows (c x k)
  __shared__ __align__(16) unsigned short Bbf[112 * 128];   // M rows (d x k)
  __shared__ float E_l[100];
  __shared__ float addA[112], wd_l[112];
  __shared__ float Cn_l[128];
  __shared__ int   crow_l[128];
  __shared__ float clsw_l[200];
  __shared__ float clsb_l[2];
  __shared__ int   lbl_l[3];
  __shared__ float En_s;

  int tid = threadIdx.x;
  int e  = blockIdx.x >> 3;
  int c0 = (blockIdx.x & 7) * 128;
  int erow = emo_idx[e];

  if (tid < 100) E_l[tid] = U[erow * 100 + tid];
  if (tid < 112) {
    bool v = tid < 100;
    addA[tid] = v ? (A[e * 100 + tid] + W3b[tid]) : 0.f;
    wd_l[tid] = v ? W3w[tid * 301 + 200] : 0.f;
  }
  if (tid < 128) { crow_l[tid] = cau_idx[c0 + tid]; Cn_l[tid] = Cn[c0 + tid]; }
  if (tid < 200) clsw_l[tid] = clsw[tid];
  if (tid < 2) clsb_l[tid] = clsb[tid];
  if (tid < 3) lbl_l[tid] = label3[e * 3 + tid];
  if (tid == 0) En_s = En[e];
  __syncthreads();

  // A stage: 128 rows x 16 slots
  for (int id = tid; id < 2048; id += 512) {
    int row = id >> 4, s = id & 15;
    int k0 = s * 8;
    short8v sv;
    const float* src = U + (size_t)crow_l[row] * 100;
    #pragma unroll
    for (int m = 0; m < 8; m++) {
      int k = k0 + m;
      sv[m] = (short)((k < 100) ? f2bf(src[k]) : 0);
    }
    *(short8v*)((char*)Abf + row * 256 + ((s ^ (row & 7)) << 4)) = sv;
  }
  // B stage: 112 rows x 16 slots;  d<100: W4*E+W2;  d==100: E;  d>100: 0
  for (int id = tid; id < 1792; id += 512) {
    int d = id >> 4, s = id & 15;
    int k0 = s * 8;
    short8v sv;
    #pragma unroll
    for (int m = 0; m < 8; m++) {
      int k = k0 + m;
      float v = 0.f;
      if (k < 100) {
        if (d < 100)       v = W3w[d * 301 + 201 + k] * E_l[k] + W3w[d * 301 + 100 + k];
        else if (d == 100) v = E_l[k];
      }
      sv[m] = (short)f2bf(v);
    }
    *(short8v*)((char*)Bbf + d * 256 + ((s ^ (d & 7)) << 4)) = sv;
  }
  __syncthreads();

  // MFMA: wave w owns c-rows [16w,16w+16); 7 d-tiles x 4 k-steps
  int wv = tid >> 6, l = tid & 63;
  int lrow = l & 15, lk = l >> 4;
  int arow = wv * 16 + lrow;
  short8v af[4];
  #pragma unroll
  for (int ks = 0; ks < 4; ks++) {
    int s = ks * 4 + lk;
    af[ks] = *(const short8v*)((const char*)Abf + arow * 256 + ((s ^ (arow & 7)) << 4));
  }
  f32x4 acc[7];
  #pragma unroll
  for (int dt = 0; dt < 7; dt++) acc[dt] = (f32x4){0.f, 0.f, 0.f, 0.f};
  #pragma unroll
  for (int dt = 0; dt < 7; dt++) {
    int brow = dt * 16 + lrow;
    #pragma unroll
    for (int ks = 0; ks < 4; ks++) {
      int s = ks * 4 + lk;
      short8v bf = *(const short8v*)((const char*)Bbf + brow * 256 + ((s ^ (brow & 7)) << 4));
      acc[dt] = __builtin_amdgcn_mfma_f32_16x16x32_bf16(af[ks], bf, acc[dt], 0, 0, 0);
    }
  }

  // epilogue (in-register): c = wv*16 + lk*4 + r ; d = dt*16 + lrow
  float dist[4];
  #pragma unroll
  for (int r = 0; r < 4; r++) {
    float dotv = __shfl(acc[6][r], (l & 48) + 4, 64);   // lane holding col d=100
    int c = wv * 16 + lk * 4 + r;
    float d2 = En_s + Cn_l[c] - 2.f * dotv;
    dist[r] = sqrtf(fmaxf(d2, 0.f));
  }
  float l0[4] = {0.f, 0.f, 0.f, 0.f}, l1[4] = {0.f, 0.f, 0.f, 0.f};
  #pragma unroll
  for (int dt = 0; dt < 7; dt++) {
    int d = dt * 16 + lrow;
    float av = addA[d], wdv = wd_l[d];
    bool valid = d < 100;
    float cw0 = valid ? clsw_l[d] : 0.f;
    float cw1 = valid ? clsw_l[100 + d] : 0.f;
    #pragma unroll
    for (int r = 0; r < 4; r++) {
      float z = acc[dt][r] + av + dist[r] * wdv;
      float h = sigf(z);
      l0[r] = fmaf(h, cw0, l0[r]);
      l1[r] = fmaf(h, cw1, l1[r]);
    }
  }
  #pragma unroll
  for (int off = 1; off < 16; off <<= 1) {
    #pragma unroll
    for (int r = 0; r < 4; r++) {
      l0[r] += __shfl_xor(l0[r], off, 64);
      l1[r] += __shfl_xor(l1[r], off, 64);
    }
  }
  if (lrow == 0) {
    #pragma unroll
    for (int r = 0; r < 4; r++) {
      int c = wv * 16 + lk * 4 + r;
      float a0 = l0[r] + clsb_l[0], a1 = l1[r] + clsb_l[1];
      float mx = fmaxf(a0, a1);
      float lse = mx + __logf(__expf(a0 - mx) + __expf(a1 - mx));
      int pair = e * 1024 + c0 + c;
      out[pair * 2]     = a0 - lse;
      out[pair * 2 + 1] = a1 - lse;
      int cidx = c0 + c;
      out[2 * NP + pair] = (lbl_l[0] == cidx || lbl_l[1] == cidx || lbl_l[2] == cidx) ? 1.f : 0.f;
    }
  }
}

extern "C" void kernel_launch(void* const* d_in, const int* in_sizes, int n_in,
                              void* d_out, int out_size, void* d_ws, size_t ws_size,
                              hipStream_t stream) {
  const float* x     = (const float*)d_in[0];
  const int*   lens  = (const int*)d_in[1];
  const int*   emo   = (const int*)d_in[2];
  const int*   cau   = (const int*)d_in[3];
  const int*   lbl3  = (const int*)d_in[4];
  const float* Wih_f = (const float*)d_in[5];
  const float* Whh_f = (const float*)d_in[6];
  const float* bih_f = (const float*)d_in[7];
  const float* bhh_f = (const float*)d_in[8];
  const float* Wih_b = (const float*)d_in[9];
  // d_in[10] = W_hh_b unused: h0 = 0
  const float* bih_b = (const float*)d_in[11];
  const float* bhh_b = (const float*)d_in[12];
  const float* W3w   = (const float*)d_in[13];
  const float* W3b   = (const float*)d_in[14];
  const float* clsw  = (const float*)d_in[15];
  const float* clsb  = (const float*)d_in[16];
  float* out = (float*)d_out;

  char* ws = (char*)d_ws;
  float* U       = (float*)ws;               // 2048*100 f = 819200 B
  int*   emo_idx = (int*)(ws + 819200);      // 1024 i
  int*   cau_idx = (int*)(ws + 823296);      // 1024 i
  float* A       = (float*)(ws + 827392);    // 1024*100 f = 409600 B
  float* En      = (float*)(ws + 1236992);   // 1024 f
  float* Cn      = (float*)(ws + 1241088);   // 1024 f

  hipLaunchKernelGGL(k_build_idx, dim3(1), dim3(256), 0, stream, emo, cau, emo_idx, cau_idx);
  hipLaunchKernelGGL(k_lstm_fwd, dim3(256), dim3(256), 0, stream,
                     x, lens, Wih_f, Whh_f, bih_f, bhh_f, U);
  hipLaunchKernelGGL(k_lstm_bwd, dim3(256), dim3(256), 0, stream,
                     x, lens, Wih_b, bih_b, bhh_b, U);
  hipLaunchKernelGGL(k_prep, dim3(2048), dim3(128), 0, stream,
                     U, emo_idx, cau_idx, W3w, A, En, Cn);
  hipLaunchKernelGGL(k_pair, dim3(8192), dim3(512), 0, stream,
                     U, emo_idx, cau_idx, A, En, Cn, W3w, W3b, clsw, clsb, lbl3, out);
}

// Round 4
// 1026.780 us; speedup vs baseline: 3.1586x; 2.1284x over previous
//
#include <hip/hip_runtime.h>
#include <hip/hip_bf16.h>
#include <math.h>

#define B_  2048
#define L_  128
#define D_  100
#define H_  50
#define NE  1024
#define NC  1024
#define NP  (NE*NC)
#define GSTR 212   // gbuf row stride (floats): 2-way max bank aliasing on G writes

typedef __attribute__((ext_vector_type(8))) _Float16 half8v;
typedef __attribute__((ext_vector_type(4))) _Float16 half4v;
typedef __attribute__((ext_vector_type(4))) float f32x4;

__device__ __forceinline__ float sigf(float x) { return 1.f / (1.f + __expf(-x)); }

// ---------------- kernel 1: flatnonzero index lists ----------------
__global__ __launch_bounds__(256) void k_build_idx(const int* __restrict__ emo,
                                                   const int* __restrict__ cau,
                                                   int* __restrict__ emo_idx,
                                                   int* __restrict__ cau_idx) {
  __shared__ int pe[256], pc[256];
  int tid = threadIdx.x;
  int ce = 0, cc = 0;
  int base = tid * 8;
  for (int r = 0; r < 8; r++) { ce += (emo[base + r] != 0); cc += (cau[base + r] != 0); }
  pe[tid] = ce; pc[tid] = cc;
  __syncthreads();
  if (tid == 0) {
    int re = 0, rc = 0;
    for (int i = 0; i < 256; i++) {
      int t = pe[i]; pe[i] = re; re += t;
      t = pc[i]; pc[i] = rc; rc += t;
    }
  }
  __syncthreads();
  int oe = pe[tid], oc = pc[tid];
  for (int r = 0; r < 8; r++) {
    int idx = base + r;
    if (emo[idx] != 0) emo_idx[oe++] = idx;
    if (cau[idx] != 0) cau_idx[oc++] = idx;
  }
}

// ---------------- kernel 2: masked forward LSTM via fp16 MFMA ----------------
// 8 batches/block (M rows 8..15 are zero pad), 256 blocks, 4 waves.
// Per t: G(16x208) = xs_t(16x128)@WihT + hs(16x64)@WhhT  (fp16 in, fp32 out)
// Wave w owns n-tiles n = w + 4i (13 tiles of 16 gates).
// x double-buffered in LDS; loads issued at phase (a), LDS-written at (f) -> latency
// hides under MFMA + nonlinearity. c-state in registers of the nonlin thread.
__global__ __launch_bounds__(256) void k_lstm_fwd(const float* __restrict__ x,
                                                  const int* __restrict__ lens,
                                                  const float* __restrict__ Wih,
                                                  const float* __restrict__ Whh,
                                                  const float* __restrict__ bih,
                                                  const float* __restrict__ bhh,
                                                  float* __restrict__ U) {
  __shared__ __align__(16) _Float16 Wihf[13 * 4 * 64 * 8];  // 52 KB  B-frags (x part)
  __shared__ __align__(16) _Float16 Whhf[13 * 2 * 64 * 8];  // 26 KB  B-frags (h part)
  __shared__ __align__(16) _Float16 xs[2][16 * 128];        // 8 KB   A rows (swizzled slots)
  __shared__ __align__(16) _Float16 hs[16 * 64];            // 2 KB   h fp16 (swizzled slots)
  __shared__ float gbuf[16 * GSTR];                         // 13.6 KB gate values fp32
  __shared__ float bias_l[200];
  __shared__ int len_l[8];
  int tid = threadIdx.x;
  int b0 = blockIdx.x * 8;

  // --- stage W_ih fragments: elem(n,ks,l,e) = Wih[j=n*16+(l&15)][k=ks*32+(l>>4)*8+e]
  for (int id = tid; id < 13 * 4 * 64; id += 256) {
    int l = id & 63, ks = (id >> 6) & 3, n = id >> 8;
    int j = n * 16 + (l & 15);
    int kb = ks * 32 + (l >> 4) * 8;
    half8v v;
    #pragma unroll
    for (int e = 0; e < 8; e++) {
      int k = kb + e;
      v[e] = (_Float16)((j < 200 && k < 100) ? Wih[j * 100 + k] : 0.f);
    }
    *(half8v*)&Wihf[id * 8] = v;
  }
  for (int id = tid; id < 13 * 2 * 64; id += 256) {
    int l = id & 63, ks = (id >> 6) & 1, n = id >> 7;
    int j = n * 16 + (l & 15);
    int kb = ks * 32 + (l >> 4) * 8;
    half8v v;
    #pragma unroll
    for (int e = 0; e < 8; e++) {
      int k = kb + e;
      v[e] = (_Float16)((j < 200 && k < 50) ? Whh[j * 50 + k] : 0.f);
    }
    *(half8v*)&Whhf[id * 8] = v;
  }
  if (tid < 200) bias_l[tid] = bih[tid] + bhh[tid];
  if (tid < 8) len_l[tid] = lens[b0 + tid];
  // zero xs (both buffers; keeps k>=100 pad zero) and hs (h0=0, hk>=50 pad)
  for (int id = tid; id < 512; id += 256) ((float4*)xs)[id] = make_float4(0.f, 0.f, 0.f, 0.f);
  for (int id = tid; id < 128; id += 256) ((float4*)hs)[id] = make_float4(0.f, 0.f, 0.f, 0.f);
  __syncthreads();

  int maxlen = 1;
  #pragma unroll
  for (int b = 0; b < 8; b++) maxlen = max(maxlen, len_l[b]);

  int wv = tid >> 6, l = tid & 63;
  int lrow = l & 15, lk = l >> 4;

  // prologue: stage xs[0] for t=0
  {
    if (tid < 200) {
      int row = tid / 25, kq = tid % 25;
      float4 xv = *(const float4*)(x + (size_t)(b0 + row) * (L_ * D_) + kq * 4);
      half4v h4 = { (_Float16)xv.x, (_Float16)xv.y, (_Float16)xv.z, (_Float16)xv.w };
      *(half4v*)((char*)&xs[0][0] + row * 256 + (((kq >> 1) ^ (row & 7)) << 4) + (kq & 1) * 8) = h4;
    }
    __syncthreads();
  }

  float cst[2] = {0.f, 0.f};   // cell state for this thread's (u,b) pairs
  for (int t = 0; t < maxlen; t++) {
    int cur = t & 1, nxt = cur ^ 1;
    // (a) issue x prefetch for t+1 (values land in pf; consumed at (f))
    float4 pf;
    int prow = 0, pkq = 0;
    bool pvalid = tid < 200;
    if (pvalid) {
      int tp = min(t + 1, L_ - 1);
      prow = tid / 25; pkq = tid % 25;
      pf = *(const float4*)(x + (size_t)(b0 + prow) * (L_ * D_) + tp * D_ + pkq * 4);
    }
    // (b) MFMA: A frags from xs[cur] + hs, B frags from W LDS
    half8v ax[4], ah[2];
    #pragma unroll
    for (int ks = 0; ks < 4; ks++)
      ax[ks] = *(const half8v*)((const char*)&xs[cur][0] + lrow * 256 + (((ks * 4 + lk) ^ (lrow & 7)) << 4));
    #pragma unroll
    for (int ks = 0; ks < 2; ks++)
      ah[ks] = *(const half8v*)((const char*)hs + lrow * 128 + (((ks * 4 + lk) ^ (lrow & 7)) << 4));
    f32x4 acc[4];
    #pragma unroll
    for (int i = 0; i < 4; i++) acc[i] = (f32x4){0.f, 0.f, 0.f, 0.f};
    #pragma unroll
    for (int i = 0; i < 4; i++) {
      int n = wv + 4 * i;
      if (n < 13) {
        #pragma unroll
        for (int ks = 0; ks < 4; ks++) {
          half8v bf = *(const half8v*)&Wihf[(((n * 4 + ks) * 64) + l) * 8];
          acc[i] = __builtin_amdgcn_mfma_f32_16x16x32_f16(ax[ks], bf, acc[i], 0, 0, 0);
        }
        #pragma unroll
        for (int ks = 0; ks < 2; ks++) {
          half8v bf = *(const half8v*)&Whhf[(((n * 2 + ks) * 64) + l) * 8];
          acc[i] = __builtin_amdgcn_mfma_f32_16x16x32_f16(ah[ks], bf, acc[i], 0, 0, 0);
        }
      }
    }
    // (c) spill gates to gbuf (rows 8..15 are pad garbage, never read)
    #pragma unroll
    for (int i = 0; i < 4; i++) {
      int n = wv + 4 * i;
      if (n < 13) {
        #pragma unroll
        for (int q = 0; q < 4; q++)
          gbuf[(lk * 4 + q) * GSTR + n * 16 + lrow] = acc[i][q];
      }
    }
    __syncthreads();   // (d)
    // (e) nonlinearity + state update; pairs p = tid, tid+256 over 400 = 8b x 50u
    #pragma unroll
    for (int r = 0; r < 2; r++) {
      int p = tid + 256 * r;
      if (p < 400) {
        int u = p % 50, b = p / 50;
        if (t < len_l[b]) {
          float gi = gbuf[b * GSTR + u]        + bias_l[u];
          float gf = gbuf[b * GSTR + 50 + u]   + bias_l[50 + u];
          float gg = gbuf[b * GSTR + 100 + u]  + bias_l[100 + u];
          float go = gbuf[b * GSTR + 150 + u]  + bias_l[150 + u];
          float cn = sigf(gf) * cst[r] + sigf(gi) * tanhf(gg);
          cst[r] = cn;
          float hv = sigf(go) * tanhf(cn);
          *(_Float16*)((char*)hs + b * 128 + (((u >> 3) ^ (b & 7)) << 4) + (u & 7) * 2) = (_Float16)hv;
          if (t == len_l[b] - 1) U[(size_t)(b0 + b) * 100 + u] = hv;
        }
      }
    }
    // (f) write prefetched x into xs[nxt] (vmcnt wait lands here, hidden by (b)-(e))
    if (pvalid) {
      half4v h4 = { (_Float16)pf.x, (_Float16)pf.y, (_Float16)pf.z, (_Float16)pf.w };
      *(half4v*)((char*)&xs[nxt][0] + prow * 256 + (((pkq >> 1) ^ (prow & 7)) << 4) + (pkq & 1) * 8) = h4;
    }
    __syncthreads();   // (g)
  }
}

// ---------------- kernel 3: backward single cell (h0=c0=0 -> W_hh_b unused) ----------------
__global__ __launch_bounds__(256) void k_lstm_bwd(const float* __restrict__ x,
                                                  const int* __restrict__ lens,
                                                  const float* __restrict__ Wih,
                                                  const float* __restrict__ bih,
                                                  const float* __restrict__ bhh,
                                                  float* __restrict__ U) {
  __shared__ float W_l[100][200];
  __shared__ float bias_l[200];
  __shared__ float xs[8][100];
  __shared__ float gb[8][200];
  __shared__ int len_l[8];
  int tid = threadIdx.x;
  int b0 = blockIdx.x * 8;
  for (int id = tid; id < 20000; id += 256) { int j = id / 100, i = id % 100; W_l[i][j] = Wih[id]; }
  if (tid < 200) bias_l[tid] = bih[tid] + bhh[tid];
  if (tid < 8) len_l[tid] = lens[b0 + tid];
  __syncthreads();
  for (int id = tid; id < 800; id += 256) {
    int b = id / 100, i = id % 100;
    int t = len_l[b] - 1;
    xs[b][i] = x[(size_t)(b0 + b) * (L_ * D_) + t * D_ + i];
  }
  __syncthreads();
  int j = tid;
  if (j < 200) {
    float acc[8];
    float bj = bias_l[j];
    #pragma unroll
    for (int b = 0; b < 8; b++) acc[b] = bj;
    #pragma unroll 2
    for (int k = 0; k < 100; k++) {
      float w = W_l[k][j];
      #pragma unroll
      for (int b = 0; b < 8; b++) acc[b] = fmaf(w, xs[b][k], acc[b]);
    }
    #pragma unroll
    for (int b = 0; b < 8; b++) gb[b][j] = acc[b];
  }
  __syncthreads();
  if (tid < 200) {
    int uk = tid % 50, ub = tid / 50;
    #pragma unroll
    for (int s = 0; s < 2; s++) {
      int b = ub + 4 * s;
      float gi = gb[b][uk], gg = gb[b][100 + uk], go = gb[b][150 + uk];
      float cn = sigf(gi) * tanhf(gg);
      U[(size_t)(b0 + b) * 100 + 50 + uk] = sigf(go) * tanhf(cn);
    }
  }
}

// ---------------- kernel 4: A = E@W1^T + row norms ----------------
__global__ __launch_bounds__(128) void k_prep(const float* __restrict__ U,
                                              const int* __restrict__ emo_idx,
                                              const int* __restrict__ cau_idx,
                                              const float* __restrict__ W3w,
                                              float* __restrict__ A,
                                              float* __restrict__ En,
                                              float* __restrict__ Cn) {
  __shared__ float u[100];
  int bid = blockIdx.x;
  int tid = threadIdx.x;
  bool is_e = bid < NE;
  int i = is_e ? bid : bid - NE;
  int row = is_e ? emo_idx[i] : cau_idx[i];
  if (tid < 100) u[tid] = U[row * 100 + tid];
  __syncthreads();
  if (is_e && tid < 100) {
    float acc = 0.f;
    const float* wrow = W3w + tid * 301;
    #pragma unroll 4
    for (int k = 0; k < 100; k++) acc = fmaf(u[k], wrow[k], acc);
    A[i * 100 + tid] = acc;
  }
  if (tid < 64) {
    float v = u[tid] * u[tid];
    if (tid < 36) v += u[tid + 64] * u[tid + 64];
    for (int o = 32; o > 0; o >>= 1) v += __shfl_down(v, o);
    if (tid == 0) { if (is_e) En[i] = v; else Cn[i] = v; }
  }
}

// ---------------- kernel 5: pair via fp16 MFMA ----------------
__global__ __launch_bounds__(512) void k_pair(const float* __restrict__ U,
                                              const int* __restrict__ emo_idx,
                                              const int* __restrict__ cau_idx,
                                              const float* __restrict__ A,
                                              const float* __restrict__ En,
                                              const float* __restrict__ Cn,
                                              const float* __restrict__ W3w,
                                              const float* __restrict__ W3b,
                                              const float* __restrict__ clsw,
                                              const float* __restrict__ clsb,
                                              const int* __restrict__ label3,
                                              float* __restrict__ out) {
  __shared__ __align__(16) _Float16 Abf[128 * 128];   // C rows (c x k), swizzled 16B slots
  __shared__ __align__(16) _Float16 Bbf[112 * 128];   // M rows (d x k)
  __shared__ float E_l[100];
  __shared__ float addA[112], wd_l[112];
  __shared__ float Cn_l[128];
  __shared__ int   crow_l[128];
  __shared__ float clsw_l[200];
  __shared__ float clsb_l[2];
  __shared__ int   lbl_l[3];
  __shared__ float En_s;

  int tid = threadIdx.x;
  int e  = blockIdx.x >> 3;
  int c0 = (blockIdx.x & 7) * 128;
  int erow = emo_idx[e];

  if (tid < 100) E_l[tid] = U[erow * 100 + tid];
  if (tid < 112) {
    bool v = tid < 100;
    addA[tid] = v ? (A[e * 100 + tid] + W3b[tid]) : 0.f;
    wd_l[tid] = v ? W3w[tid * 301 + 200] : 0.f;
  }
  if (tid < 128) { crow_l[tid] = cau_idx[c0 + tid]; Cn_l[tid] = Cn[c0 + tid]; }
  if (tid < 200) clsw_l[tid] = clsw[tid];
  if (tid < 2) clsb_l[tid] = clsb[tid];
  if (tid < 3) lbl_l[tid] = label3[e * 3 + tid];
  if (tid == 0) En_s = En[e];
  __syncthreads();

  for (int id = tid; id < 2048; id += 512) {
    int row = id >> 4, s = id & 15;
    int k0 = s * 8;
    half8v sv;
    const float* src = U + (size_t)crow_l[row] * 100;
    #pragma unroll
    for (int m = 0; m < 8; m++) {
      int k = k0 + m;
      sv[m] = (k < 100) ? (_Float16)src[k] : (_Float16)0.f;
    }
    *(half8v*)((char*)Abf + row * 256 + ((s ^ (row & 7)) << 4)) = sv;
  }
  for (int id = tid; id < 1792; id += 512) {
    int d = id >> 4, s = id & 15;
    int k0 = s * 8;
    half8v sv;
    #pragma unroll
    for (int m = 0; m < 8; m++) {
      int k = k0 + m;
      float v = 0.f;
      if (k < 100) {
        if (d < 100)       v = W3w[d * 301 + 201 + k] * E_l[k] + W3w[d * 301 + 100 + k];
        else if (d == 100) v = E_l[k];
      }
      sv[m] = (_Float16)v;
    }
    *(half8v*)((char*)Bbf + d * 256 + ((s ^ (d & 7)) << 4)) = sv;
  }
  __syncthreads();

  int wv = tid >> 6, l = tid & 63;
  int lrow = l & 15, lk = l >> 4;
  int arow = wv * 16 + lrow;
  half8v af[4];
  #pragma unroll
  for (int ks = 0; ks < 4; ks++) {
    int s = ks * 4 + lk;
    af[ks] = *(const half8v*)((const char*)Abf + arow * 256 + ((s ^ (arow & 7)) << 4));
  }
  f32x4 acc[7];
  #pragma unroll
  for (int dt = 0; dt < 7; dt++) acc[dt] = (f32x4){0.f, 0.f, 0.f, 0.f};
  #pragma unroll
  for (int dt = 0; dt < 7; dt++) {
    int brow = dt * 16 + lrow;
    #pragma unroll
    for (int ks = 0; ks < 4; ks++) {
      int s = ks * 4 + lk;
      half8v bf = *(const half8v*)((const char*)Bbf + brow * 256 + ((s ^ (brow & 7)) << 4));
      acc[dt] = __builtin_amdgcn_mfma_f32_16x16x32_f16(af[ks], bf, acc[dt], 0, 0, 0);
    }
  }

  float dist[4];
  #pragma unroll
  for (int r = 0; r < 4; r++) {
    float dotv = __shfl(acc[6][r], (l & 48) + 4, 64);   // lane holding col d=100
    int c = wv * 16 + lk * 4 + r;
    float d2 = En_s + Cn_l[c] - 2.f * dotv;
    dist[r] = sqrtf(fmaxf(d2, 0.f));
  }
  float l0[4] = {0.f, 0.f, 0.f, 0.f}, l1[4] = {0.f, 0.f, 0.f, 0.f};
  #pragma unroll
  for (int dt = 0; dt < 7; dt++) {
    int d = dt * 16 + lrow;
    float av = addA[d], wdv = wd_l[d];
    bool valid = d < 100;
    float cw0 = valid ? clsw_l[d] : 0.f;
    float cw1 = valid ? clsw_l[100 + d] : 0.f;
    #pragma unroll
    for (int r = 0; r < 4; r++) {
      float z = acc[dt][r] + av + dist[r] * wdv;
      float h = sigf(z);
      l0[r] = fmaf(h, cw0, l0[r]);
      l1[r] = fmaf(h, cw1, l1[r]);
    }
  }
  #pragma unroll
  for (int off = 1; off < 16; off <<= 1) {
    #pragma unroll
    for (int r = 0; r < 4; r++) {
      l0[r] += __shfl_xor(l0[r], off, 64);
      l1[r] += __shfl_xor(l1[r], off, 64);
    }
  }
  if (lrow == 0) {
    #pragma unroll
    for (int r = 0; r < 4; r++) {
      int c = wv * 16 + lk * 4 + r;
      float a0 = l0[r] + clsb_l[0], a1 = l1[r] + clsb_l[1];
      float mx = fmaxf(a0, a1);
      float lse = mx + __logf(__expf(a0 - mx) + __expf(a1 - mx));
      int pair = e * 1024 + c0 + c;
      out[pair * 2]     = a0 - lse;
      out[pair * 2 + 1] = a1 - lse;
      int cidx = c0 + c;
      out[2 * NP + pair] = (lbl_l[0] == cidx || lbl_l[1] == cidx || lbl_l[2] == cidx) ? 1.f : 0.f;
    }
  }
}

extern "C" void kernel_launch(void* const* d_in, const int* in_sizes, int n_in,
                              void* d_out, int out_size, void* d_ws, size_t ws_size,
                              hipStream_t stream) {
  const float* x     = (const float*)d_in[0];
  const int*   lens  = (const int*)d_in[1];
  const int*   emo   = (const int*)d_in[2];
  const int*   cau   = (const int*)d_in[3];
  const int*   lbl3  = (const int*)d_in[4];
  const float* Wih_f = (const float*)d_in[5];
  const float* Whh_f = (const float*)d_in[6];
  const float* bih_f = (const float*)d_in[7];
  const float* bhh_f = (const float*)d_in[8];
  const float* Wih_b = (const float*)d_in[9];
  // d_in[10] = W_hh_b unused: h0 = 0
  const float* bih_b = (const float*)d_in[11];
  const float* bhh_b = (const float*)d_in[12];
  const float* W3w   = (const float*)d_in[13];
  const float* W3b   = (const float*)d_in[14];
  const float* clsw  = (const float*)d_in[15];
  const float* clsb  = (const float*)d_in[16];
  float* out = (float*)d_out;

  char* ws = (char*)d_ws;
  float* U       = (float*)ws;               // 2048*100 f = 819200 B
  int*   emo_idx = (int*)(ws + 819200);      // 1024 i
  int*   cau_idx = (int*)(ws + 823296);      // 1024 i
  float* A       = (float*)(ws + 827392);    // 1024*100 f = 409600 B
  float* En      = (float*)(ws + 1236992);   // 1024 f
  float* Cn      = (float*)(ws + 1241088);   // 1024 f

  hipLaunchKernelGGL(k_build_idx, dim3(1), dim3(256), 0, stream, emo, cau, emo_idx, cau_idx);
  hipLaunchKernelGGL(k_lstm_fwd, dim3(256), dim3(256), 0, stream,
                     x, lens, Wih_f, Whh_f, bih_f, bhh_f, U);
  hipLaunchKernelGGL(k_lstm_bwd, dim3(256), dim3(256), 0, stream,
                     x, lens, Wih_b, bih_b, bhh_b, U);
  hipLaunchKernelGGL(k_prep, dim3(2048), dim3(128), 0, stream,
                     U, emo_idx, cau_idx, W3w, A, En, Cn);
  hipLaunchKernelGGL(k_pair, dim3(8192), dim3(512), 0, stream,
                     U, emo_idx, cau_idx, A, En, Cn, W3w, W3b, clsw, clsb, lbl3, out);
}

// Round 6
// 635.868 us; speedup vs baseline: 5.1004x; 1.6148x over previous
//
#include <hip/hip_runtime.h>
#include <hip/hip_bf16.h>
#include <math.h>

#define B_  2048
#define L_  128
#define D_  100
#define H_  50
#define NE  1024
#define NC  1024
#define NP  (NE*NC)
#define GSTR 212   // gbuf row stride (floats)

typedef __attribute__((ext_vector_type(8))) _Float16 half8v;
typedef __attribute__((ext_vector_type(4))) _Float16 half4v;
typedef __attribute__((ext_vector_type(4))) float f32x4;

__device__ __forceinline__ float sigf(float x) { return 1.f / (1.f + __expf(-x)); }
__device__ __forceinline__ float tanhfast(float x) {
  float e = __expf(-2.f * x);
  return (1.f - e) / (1.f + e);
}
// produce -> barrier: LDS writes drained, vmcnt stays in flight (T4)
__device__ __forceinline__ void bar_sync() {
  asm volatile("s_waitcnt lgkmcnt(0)" ::: "memory");
  __builtin_amdgcn_s_barrier();
  __builtin_amdgcn_sched_barrier(0);
}

// ---------------- kernel 1: flatnonzero index lists ----------------
__global__ __launch_bounds__(256) void k_build_idx(const int* __restrict__ emo,
                                                   const int* __restrict__ cau,
                                                   int* __restrict__ emo_idx,
                                                   int* __restrict__ cau_idx) {
  __shared__ int pe[256], pc[256];
  int tid = threadIdx.x;
  int ce = 0, cc = 0;
  int base = tid * 8;
  for (int r = 0; r < 8; r++) { ce += (emo[base + r] != 0); cc += (cau[base + r] != 0); }
  pe[tid] = ce; pc[tid] = cc;
  __syncthreads();
  if (tid == 0) {
    int re = 0, rc = 0;
    for (int i = 0; i < 256; i++) {
      int t = pe[i]; pe[i] = re; re += t;
      t = pc[i]; pc[i] = rc; rc += t;
    }
  }
  __syncthreads();
  int oe = pe[tid], oc = pc[tid];
  for (int r = 0; r < 8; r++) {
    int idx = base + r;
    if (emo[idx] != 0) emo_idx[oe++] = idx;
    if (cau[idx] != 0) cau_idx[oc++] = idx;
  }
}

// ---------------- kernel 2: masked forward LSTM via fp16 MFMA ----------------
// Raw barriers: lgkmcnt(0)+s_barrier only -> x prefetch (vmcnt) spans the whole
// iteration: issue (a) ... consumed at (f) after nonlin. 2 barriers/t.
__global__ __launch_bounds__(256) void k_lstm_fwd(const float* __restrict__ x,
                                                  const int* __restrict__ lens,
                                                  const float* __restrict__ Wih,
                                                  const float* __restrict__ Whh,
                                                  const float* __restrict__ bih,
                                                  const float* __restrict__ bhh,
                                                  float* __restrict__ U) {
  __shared__ __align__(16) _Float16 Wihf[13 * 4 * 64 * 8];  // 52 KB
  __shared__ __align__(16) _Float16 Whhf[13 * 2 * 64 * 8];  // 26 KB
  __shared__ __align__(16) _Float16 xs[2][16 * 128];        // 8 KB
  __shared__ __align__(16) _Float16 hs[16 * 64];            // 2 KB
  __shared__ float gbuf[8 * GSTR];                          // 6.8 KB
  __shared__ float bias_l[200];
  __shared__ int len_l[8];
  int tid = threadIdx.x;
  int b0 = blockIdx.x * 8;

  for (int id = tid; id < 13 * 4 * 64; id += 256) {
    int l = id & 63, ks = (id >> 6) & 3, n = id >> 8;
    int j = n * 16 + (l & 15);
    int kb = ks * 32 + (l >> 4) * 8;
    half8v v;
    #pragma unroll
    for (int e = 0; e < 8; e++) {
      int k = kb + e;
      v[e] = (_Float16)((j < 200 && k < 100) ? Wih[j * 100 + k] : 0.f);
    }
    *(half8v*)&Wihf[id * 8] = v;
  }
  for (int id = tid; id < 13 * 2 * 64; id += 256) {
    int l = id & 63, ks = (id >> 6) & 1, n = id >> 7;
    int j = n * 16 + (l & 15);
    int kb = ks * 32 + (l >> 4) * 8;
    half8v v;
    #pragma unroll
    for (int e = 0; e < 8; e++) {
      int k = kb + e;
      v[e] = (_Float16)((j < 200 && k < 50) ? Whh[j * 50 + k] : 0.f);
    }
    *(half8v*)&Whhf[id * 8] = v;
  }
  if (tid < 200) bias_l[tid] = bih[tid] + bhh[tid];
  if (tid < 8) len_l[tid] = lens[b0 + tid];
  for (int id = tid; id < 512; id += 256) ((float4*)xs)[id] = make_float4(0.f, 0.f, 0.f, 0.f);
  for (int id = tid; id < 128; id += 256) ((float4*)hs)[id] = make_float4(0.f, 0.f, 0.f, 0.f);
  __syncthreads();

  int maxlen = 1;
  #pragma unroll
  for (int b = 0; b < 8; b++) maxlen = max(maxlen, len_l[b]);

  int wv = tid >> 6, l = tid & 63;
  int lrow = l & 15, lk = l >> 4;
  bool pvalid = tid < 200;
  int prow = tid / 25, pkq = tid % 25;

  // prologue: stage xs[0] for t=0
  if (pvalid) {
    float4 xv = *(const float4*)(x + (size_t)(b0 + prow) * (L_ * D_) + pkq * 4);
    half4v h4 = { (_Float16)xv.x, (_Float16)xv.y, (_Float16)xv.z, (_Float16)xv.w };
    *(half4v*)((char*)&xs[0][0] + prow * 256 + (((pkq >> 1) ^ (prow & 7)) << 4) + (pkq & 1) * 8) = h4;
  }
  __syncthreads();

  float cst[2] = {0.f, 0.f};
  for (int t = 0; t < maxlen; t++) {
    int cur = t & 1, nxt = cur ^ 1;
    // (a) issue x prefetch for t+1
    float4 pf;
    if (pvalid) {
      int tp = min(t + 1, L_ - 1);
      pf = *(const float4*)(x + (size_t)(b0 + prow) * (L_ * D_) + tp * D_ + pkq * 4);
    }
    // (b) MFMA phase
    half8v ax[4], ah[2];
    #pragma unroll
    for (int ks = 0; ks < 4; ks++)
      ax[ks] = *(const half8v*)((const char*)&xs[cur][0] + lrow * 256 + (((ks * 4 + lk) ^ (lrow & 7)) << 4));
    #pragma unroll
    for (int ks = 0; ks < 2; ks++)
      ah[ks] = *(const half8v*)((const char*)hs + lrow * 128 + (((ks * 4 + lk) ^ (lrow & 7)) << 4));
    f32x4 acc[4];
    #pragma unroll
    for (int i = 0; i < 4; i++) acc[i] = (f32x4){0.f, 0.f, 0.f, 0.f};
    #pragma unroll
    for (int i = 0; i < 4; i++) {
      int n = wv + 4 * i;
      if (n < 13) {
        #pragma unroll
        for (int ks = 0; ks < 4; ks++) {
          half8v bf = *(const half8v*)&Wihf[(((n * 4 + ks) * 64) + l) * 8];
          acc[i] = __builtin_amdgcn_mfma_f32_16x16x32_f16(ax[ks], bf, acc[i], 0, 0, 0);
        }
        #pragma unroll
        for (int ks = 0; ks < 2; ks++) {
          half8v bf = *(const half8v*)&Whhf[(((n * 2 + ks) * 64) + l) * 8];
          acc[i] = __builtin_amdgcn_mfma_f32_16x16x32_f16(ah[ks], bf, acc[i], 0, 0, 0);
        }
      }
    }
    // (c) gate spill (only c-rows 0..7 are real batches)
    if (lk < 2) {
      #pragma unroll
      for (int i = 0; i < 4; i++) {
        int n = wv + 4 * i;
        if (n < 13) {
          #pragma unroll
          for (int q = 0; q < 4; q++)
            gbuf[(lk * 4 + q) * GSTR + n * 16 + lrow] = acc[i][q];
        }
      }
    }
    bar_sync();   // (d) — vmcnt NOT drained, pf still in flight
    // (e) nonlinearity + state update
    #pragma unroll
    for (int r = 0; r < 2; r++) {
      int p = tid + 256 * r;
      if (p < 400) {
        int u = p % 50, b = p / 50;
        if (t < len_l[b]) {
          float gi = gbuf[b * GSTR + u]       + bias_l[u];
          float gf = gbuf[b * GSTR + 50 + u]  + bias_l[50 + u];
          float gg = gbuf[b * GSTR + 100 + u] + bias_l[100 + u];
          float go = gbuf[b * GSTR + 150 + u] + bias_l[150 + u];
          float cn = sigf(gf) * cst[r] + sigf(gi) * tanhfast(gg);
          cst[r] = cn;
          float hv = sigf(go) * tanhfast(cn);
          *(_Float16*)((char*)hs + b * 128 + (((u >> 3) ^ (b & 7)) << 4) + (u & 7) * 2) = (_Float16)hv;
          if (t == len_l[b] - 1) U[(size_t)(b0 + b) * 100 + u] = hv;
        }
      }
    }
    // (f) write prefetched x into xs[nxt] — vmcnt wait lands here, covered by (b)-(e)
    if (pvalid) {
      half4v h4 = { (_Float16)pf.x, (_Float16)pf.y, (_Float16)pf.z, (_Float16)pf.w };
      *(half4v*)((char*)&xs[nxt][0] + prow * 256 + (((pkq >> 1) ^ (prow & 7)) << 4) + (pkq & 1) * 8) = h4;
    }
    bar_sync();   // (g)
  }
}

// ---------------- kernel 3: backward single cell (h0=c0=0 -> W_hh_b unused) ----------------
__global__ __launch_bounds__(256) void k_lstm_bwd(const float* __restrict__ x,
                                                  const int* __restrict__ lens,
                                                  const float* __restrict__ Wih,
                                                  const float* __restrict__ bih,
                                                  const float* __restrict__ bhh,
                                                  float* __restrict__ U) {
  __shared__ float W_l[100][200];
  __shared__ float bias_l[200];
  __shared__ float xs[8][100];
  __shared__ float gb[8][200];
  __shared__ int len_l[8];
  int tid = threadIdx.x;
  int b0 = blockIdx.x * 8;
  for (int id = tid; id < 20000; id += 256) { int j = id / 100, i = id % 100; W_l[i][j] = Wih[id]; }
  if (tid < 200) bias_l[tid] = bih[tid] + bhh[tid];
  if (tid < 8) len_l[tid] = lens[b0 + tid];
  __syncthreads();
  for (int id = tid; id < 800; id += 256) {
    int b = id / 100, i = id % 100;
    int t = len_l[b] - 1;
    xs[b][i] = x[(size_t)(b0 + b) * (L_ * D_) + t * D_ + i];
  }
  __syncthreads();
  int j = tid;
  if (j < 200) {
    float acc[8];
    float bj = bias_l[j];
    #pragma unroll
    for (int b = 0; b < 8; b++) acc[b] = bj;
    #pragma unroll 2
    for (int k = 0; k < 100; k++) {
      float w = W_l[k][j];
      #pragma unroll
      for (int b = 0; b < 8; b++) acc[b] = fmaf(w, xs[b][k], acc[b]);
    }
    #pragma unroll
    for (int b = 0; b < 8; b++) gb[b][j] = acc[b];
  }
  __syncthreads();
  if (tid < 200) {
    int uk = tid % 50, ub = tid / 50;
    #pragma unroll
    for (int s = 0; s < 2; s++) {
      int b = ub + 4 * s;
      float gi = gb[b][uk], gg = gb[b][100 + uk], go = gb[b][150 + uk];
      float cn = sigf(gi) * tanhfast(gg);
      U[(size_t)(b0 + b) * 100 + 50 + uk] = sigf(go) * tanhfast(cn);
    }
  }
}

// ---------------- kernel 4: A = E@W1^T, row norms, Cfrag (fp16 A-fragments) ----
__global__ __launch_bounds__(128) void k_prep(const float* __restrict__ U,
                                              const int* __restrict__ emo_idx,
                                              const int* __restrict__ cau_idx,
                                              const float* __restrict__ W3w,
                                              float* __restrict__ A,
                                              float* __restrict__ En,
                                              float* __restrict__ Cn,
                                              _Float16* __restrict__ Cfrag) {
  __shared__ float u[100];
  int bid = blockIdx.x;
  int tid = threadIdx.x;
  bool is_e = bid < NE;
  int i = is_e ? bid : bid - NE;
  int row = is_e ? emo_idx[i] : cau_idx[i];
  if (tid < 100) u[tid] = U[row * 100 + tid];
  __syncthreads();
  if (is_e && tid < 100) {
    float acc = 0.f;
    const float* wrow = W3w + tid * 301;
    #pragma unroll 4
    for (int k = 0; k < 100; k++) acc = fmaf(u[k], wrow[k], acc);
    A[i * 100 + tid] = acc;
  }
  if (!is_e && tid < 16) {
    // fragment layout: Cfrag[((ct*4+ks)*64 + lrow + 16*seg)*8 + e] = C[ct*16+lrow][ks*32+seg*8+e]
    int ct = i >> 4, lrow = i & 15;
    int ks = tid >> 2, seg = tid & 3;
    half8v v;
    #pragma unroll
    for (int e2 = 0; e2 < 8; e2++) {
      int k = tid * 8 + e2;
      v[e2] = (_Float16)((k < 100) ? u[k] : 0.f);
    }
    *(half8v*)(Cfrag + ((size_t)((ct * 4 + ks) * 64 + lrow + 16 * seg)) * 8) = v;
  }
  if (tid < 64) {
    float v = u[tid] * u[tid];
    if (tid < 36) v += u[tid + 64] * u[tid + 64];
    for (int o = 32; o > 0; o >>= 1) v += __shfl_down(v, o);
    if (tid == 0) { if (is_e) En[i] = v; else Cn[i] = v; }
  }
}

// ---------------- kernel 5: pair via fp16 MFMA, one e per block, all 1024 c ----
__global__ __launch_bounds__(256) void k_pair(const float* __restrict__ U,
                                              const int* __restrict__ emo_idx,
                                              const float* __restrict__ A,
                                              const float* __restrict__ En,
                                              const float* __restrict__ Cn,
                                              const float* __restrict__ W3w,
                                              const float* __restrict__ W3b,
                                              const float* __restrict__ clsw,
                                              const float* __restrict__ clsb,
                                              const int* __restrict__ label3,
                                              const _Float16* __restrict__ Cfrag,
                                              float* __restrict__ out) {
  __shared__ __align__(16) _Float16 Bbf[7 * 4 * 64 * 8];  // 28 KB, frag layout
  __shared__ float E_l[100];
  __shared__ float addA[112], wd_l[112];
  __shared__ float Cn_l[1024];
  __shared__ float clsw_l[200];
  __shared__ float clsb_l[2];
  __shared__ int   lbl_l[3];
  __shared__ float En_s;

  int tid = threadIdx.x;
  int e = blockIdx.x;
  int erow = emo_idx[e];

  if (tid < 100) E_l[tid] = U[erow * 100 + tid];
  if (tid < 112) {
    bool v = tid < 100;
    addA[tid] = v ? (A[e * 100 + tid] + W3b[tid]) : 0.f;
    wd_l[tid] = v ? W3w[tid * 301 + 200] : 0.f;
  }
  for (int id = tid; id < 1024; id += 256) Cn_l[id] = Cn[id];
  if (tid < 200) clsw_l[tid] = clsw[tid];
  if (tid < 2) clsb_l[tid] = clsb[tid];
  if (tid < 3) lbl_l[tid] = label3[e * 3 + tid];
  if (tid == 0) En_s = En[e];
  __syncthreads();

  // stage B (per e, once): B[d][k] = W4[d,k]*E[k]+W2[d,k]; row100 = E; rows>100 = 0
  for (int id = tid; id < 1792; id += 256) {
    int l = id & 63, ks = (id >> 6) & 3, dt = id >> 8;
    int d = dt * 16 + (l & 15);
    int kb = ks * 32 + (l >> 4) * 8;
    half8v v;
    #pragma unroll
    for (int m = 0; m < 8; m++) {
      int k = kb + m;
      float f = 0.f;
      if (k < 100) {
        if (d < 100)       f = W3w[d * 301 + 201 + k] * E_l[k] + W3w[d * 301 + 100 + k];
        else if (d == 100) f = E_l[k];
      }
      v[m] = (_Float16)f;
    }
    *(half8v*)&Bbf[id * 8] = v;
  }
  __syncthreads();

  int wv = tid >> 6, l = tid & 63;
  int lrow = l & 15, lk = l >> 4;
  for (int g = 0; g < 4; g++) {
    int ctb = wv * 16 + g * 4;                 // this wave's 4 c-tiles
    f32x4 acc[4][7];
    #pragma unroll
    for (int tt = 0; tt < 4; tt++)
      #pragma unroll
      for (int dt = 0; dt < 7; dt++) acc[tt][dt] = (f32x4){0.f, 0.f, 0.f, 0.f};
    #pragma unroll
    for (int ks = 0; ks < 4; ks++) {
      half8v af[4];
      #pragma unroll
      for (int tt = 0; tt < 4; tt++)
        af[tt] = *(const half8v*)(Cfrag + ((size_t)(((ctb + tt) * 4 + ks) * 64 + l)) * 8);
      #pragma unroll
      for (int dt = 0; dt < 7; dt++) {
        half8v bf = *(const half8v*)&Bbf[((dt * 4 + ks) * 64 + l) * 8];
        #pragma unroll
        for (int tt = 0; tt < 4; tt++)
          acc[tt][dt] = __builtin_amdgcn_mfma_f32_16x16x32_f16(af[tt], bf, acc[tt][dt], 0, 0, 0);
      }
    }
    // epilogue per c-tile
    #pragma unroll
    for (int tt = 0; tt < 4; tt++) {
      int ct = ctb + tt;
      float dist[4];
      #pragma unroll
      for (int r = 0; r < 4; r++) {
        float dotv = __shfl(acc[tt][6][r], (l & 48) + 4, 64);   // lane with d=100
        int c = ct * 16 + lk * 4 + r;
        float d2 = En_s + Cn_l[c] - 2.f * dotv;
        dist[r] = sqrtf(fmaxf(d2, 0.f));
      }
      float l0[4] = {0.f, 0.f, 0.f, 0.f}, l1[4] = {0.f, 0.f, 0.f, 0.f};
      #pragma unroll
      for (int dt = 0; dt < 7; dt++) {
        int d = dt * 16 + lrow;
        float av = addA[d], wdv = wd_l[d];
        bool valid = d < 100;
        float cw0 = valid ? clsw_l[d] : 0.f;
        float cw1 = valid ? clsw_l[100 + d] : 0.f;
        #pragma unroll
        for (int r = 0; r < 4; r++) {
          float z = acc[tt][dt][r] + av + dist[r] * wdv;
          float h = sigf(z);
          l0[r] = fmaf(h, cw0, l0[r]);
          l1[r] = fmaf(h, cw1, l1[r]);
        }
      }
      #pragma unroll
      for (int off = 1; off < 16; off <<= 1) {
        #pragma unroll
        for (int r = 0; r < 4; r++) {
          l0[r] += __shfl_xor(l0[r], off, 64);
          l1[r] += __shfl_xor(l1[r], off, 64);
        }
      }
      if (lrow == 0) {
        #pragma unroll
        for (int r = 0; r < 4; r++) {
          int c = ct * 16 + lk * 4 + r;
          float a0 = l0[r] + clsb_l[0], a1 = l1[r] + clsb_l[1];
          float mx = fmaxf(a0, a1);
          float lse = mx + __logf(__expf(a0 - mx) + __expf(a1 - mx));
          int pair = e * 1024 + c;
          out[pair * 2]     = a0 - lse;
          out[pair * 2 + 1] = a1 - lse;
          out[2 * NP + pair] = (lbl_l[0] == c || lbl_l[1] == c || lbl_l[2] == c) ? 1.f : 0.f;
        }
      }
    }
  }
}

extern "C" void kernel_launch(void* const* d_in, const int* in_sizes, int n_in,
                              void* d_out, int out_size, void* d_ws, size_t ws_size,
                              hipStream_t stream) {
  const float* x     = (const float*)d_in[0];
  const int*   lens  = (const int*)d_in[1];
  const int*   emo   = (const int*)d_in[2];
  const int*   cau   = (const int*)d_in[3];
  const int*   lbl3  = (const int*)d_in[4];
  const float* Wih_f = (const float*)d_in[5];
  const float* Whh_f = (const float*)d_in[6];
  const float* bih_f = (const float*)d_in[7];
  const float* bhh_f = (const float*)d_in[8];
  const float* Wih_b = (const float*)d_in[9];
  // d_in[10] = W_hh_b unused: h0 = 0
  const float* bih_b = (const float*)d_in[11];
  const float* bhh_b = (const float*)d_in[12];
  const float* W3w   = (const float*)d_in[13];
  const float* W3b   = (const float*)d_in[14];
  const float* clsw  = (const float*)d_in[15];
  const float* clsb  = (const float*)d_in[16];
  float* out = (float*)d_out;

  char* ws = (char*)d_ws;
  float*     U       = (float*)ws;               // 2048*100 f = 819200 B
  int*       emo_idx = (int*)(ws + 819200);      // 1024 i
  int*       cau_idx = (int*)(ws + 823296);      // 1024 i
  float*     A       = (float*)(ws + 827392);    // 1024*100 f = 409600 B
  float*     En      = (float*)(ws + 1236992);   // 1024 f
  float*     Cn      = (float*)(ws + 1241088);   // 1024 f
  _Float16*  Cfrag   = (_Float16*)(ws + 1245184);// 1024*128 h = 262144 B

  hipLaunchKernelGGL(k_build_idx, dim3(1), dim3(256), 0, stream, emo, cau, emo_idx, cau_idx);
  hipLaunchKernelGGL(k_lstm_fwd, dim3(256), dim3(256), 0, stream,
                     x, lens, Wih_f, Whh_f, bih_f, bhh_f, U);
  hipLaunchKernelGGL(k_lstm_bwd, dim3(256), dim3(256), 0, stream,
                     x, lens, Wih_b, bih_b, bhh_b, U);
  hipLaunchKernelGGL(k_prep, dim3(2048), dim3(128), 0, stream,
                     U, emo_idx, cau_idx, W3w, A, En, Cn, Cfrag);
  hipLaunchKernelGGL(k_pair, dim3(1024), dim3(256), 0, stream,
                     U, emo_idx, A, En, Cn, W3w, W3b, clsw, clsb, lbl3, Cfrag, out);
}

// Round 8
// 581.803 us; speedup vs baseline: 5.5743x; 1.0929x over previous
//
#include <hip/hip_runtime.h>
#include <hip/hip_bf16.h>
#include <math.h>

#define B_  2048
#define L_  128
#define D_  100
#define H_  50
#define NE  1024
#define NC  1024
#define NP  (NE*NC)
#define GSTR 212   // gbuf row stride (floats)

typedef __attribute__((ext_vector_type(8))) _Float16 half8v;
typedef __attribute__((ext_vector_type(4))) _Float16 half4v;
typedef __attribute__((ext_vector_type(4))) float f32x4;

__device__ __forceinline__ float sigf(float x) { return 1.f / (1.f + __expf(-x)); }
__device__ __forceinline__ float tanhfast(float x) {
  float e = __expf(-2.f * x);
  return (1.f - e) / (1.f + e);
}
// barrier draining LDS only; vmcnt stays in flight (T4)
__device__ __forceinline__ void bar_sync() {
  asm volatile("s_waitcnt lgkmcnt(0)" ::: "memory");
  __builtin_amdgcn_s_barrier();
  __builtin_amdgcn_sched_barrier(0);
}

// ---------------- kernel 0: one-time weight repack (kills all W3w/W scatter) ----
// WfG  : fwd-LSTM fp16 B-fragments. units [0,3328): Wih (n,ks,l); [3328,4992): Whh
// W4f/W2f: k_pair B-source fp32 in frag order; d==100 encoded as W4=1,W2=0 -> row=E
// W1T  : W3w[:,0:100] transposed (k-major) for k_prep
// Wd   : W3w[:,200]
__global__ __launch_bounds__(256) void k_wfrag(const float* __restrict__ Wih,
                                               const float* __restrict__ Whh,
                                               const float* __restrict__ W3w,
                                               _Float16* __restrict__ WfG,
                                               float* __restrict__ W4f,
                                               float* __restrict__ W2f,
                                               float* __restrict__ W1T,
                                               float* __restrict__ Wd) {
  int gid = blockIdx.x * 256 + threadIdx.x;
  int nthr = gridDim.x * 256;
  for (int id = gid; id < 4992; id += nthr) {
    half8v v;
    if (id < 3328) {
      int l = id & 63, ks = (id >> 6) & 3, n = id >> 8;
      int j = n * 16 + (l & 15), kb = ks * 32 + (l >> 4) * 8;
      #pragma unroll
      for (int e = 0; e < 8; e++) {
        int k = kb + e;
        v[e] = (_Float16)((j < 200 && k < 100) ? Wih[j * 100 + k] : 0.f);
      }
    } else {
      int id2 = id - 3328;
      int l = id2 & 63, ks = (id2 >> 6) & 1, n = id2 >> 7;
      int j = n * 16 + (l & 15), kb = ks * 32 + (l >> 4) * 8;
      #pragma unroll
      for (int e = 0; e < 8; e++) {
        int k = kb + e;
        v[e] = (_Float16)((j < 200 && k < 50) ? Whh[j * 50 + k] : 0.f);
      }
    }
    *(half8v*)(WfG + (size_t)id * 8) = v;
  }
  for (int id = gid; id < 1792; id += nthr) {
    int l = id & 63, ks = (id >> 6) & 3, dt = id >> 8;
    int d = dt * 16 + (l & 15), kb = ks * 32 + (l >> 4) * 8;
    #pragma unroll
    for (int m = 0; m < 8; m++) {
      int k = kb + m;
      float w4 = 0.f, w2 = 0.f;
      if (k < 100) {
        if (d < 100)       { w4 = W3w[d * 301 + 201 + k]; w2 = W3w[d * 301 + 100 + k]; }
        else if (d == 100) { w4 = 1.f; }
      }
      W4f[(size_t)id * 8 + m] = w4;
      W2f[(size_t)id * 8 + m] = w2;
    }
  }
  for (int id = gid; id < 10000; id += nthr) {
    int k = id / 100, d = id % 100;
    W1T[id] = W3w[d * 301 + k];
  }
  for (int id = gid; id < 100; id += nthr) Wd[id] = W3w[id * 301 + 200];
}

// ---------------- kernel 1: flatnonzero index lists (shfl scan) ----------------
__global__ __launch_bounds__(256) void k_build_idx(const int* __restrict__ emo,
                                                   const int* __restrict__ cau,
                                                   int* __restrict__ emo_idx,
                                                   int* __restrict__ cau_idx) {
  __shared__ int wsum_e[4], wsum_c[4];
  int tid = threadIdx.x, lane = tid & 63, wv = tid >> 6;
  int base = tid * 8;
  int fe[8], fc[8];
  int ce = 0, cc = 0;
  #pragma unroll
  for (int r = 0; r < 8; r++) {
    fe[r] = (emo[base + r] != 0); ce += fe[r];
    fc[r] = (cau[base + r] != 0); cc += fc[r];
  }
  int se = ce, sc = cc;
  for (int o = 1; o < 64; o <<= 1) {
    int ve = __shfl_up(se, o), vc = __shfl_up(sc, o);
    if (lane >= o) { se += ve; sc += vc; }
  }
  if (lane == 63) { wsum_e[wv] = se; wsum_c[wv] = sc; }
  __syncthreads();
  int obe = 0, obc = 0;
  for (int w = 0; w < wv; w++) { obe += wsum_e[w]; obc += wsum_c[w]; }
  int oe = obe + se - ce, oc = obc + sc - cc;
  #pragma unroll
  for (int r = 0; r < 8; r++) {
    if (fe[r]) emo_idx[oe++] = base + r;
    if (fc[r]) cau_idx[oc++] = base + r;
  }
}

// ---------------- kernel 2: masked forward LSTM, fp16 MFMA, 16 waves ----------
// 1024 threads: wave wv<13 owns n-tile wv (16 gates). Threads >=824 prefetch x.
// Threads <400 do nonlinearity (one (b,u) each, cell state in register).
__global__ __launch_bounds__(1024) void k_lstm_fwd(const float* __restrict__ x,
                                                   const int* __restrict__ lens,
                                                   const _Float16* __restrict__ WfG,
                                                   const float* __restrict__ bih,
                                                   const float* __restrict__ bhh,
                                                   float* __restrict__ U) {
  __shared__ __align__(16) _Float16 Wf[4992 * 8];       // 78 KB, frag layout
  __shared__ __align__(16) _Float16 xs[2][16 * 128];    // 8 KB
  __shared__ __align__(16) _Float16 hs[16 * 64];        // 2 KB
  __shared__ float gbuf[8 * GSTR];                      // 6.8 KB
  __shared__ float bias_l[200];
  __shared__ int len_l[8];
  int tid = threadIdx.x;
  int b0 = blockIdx.x * 8;

  for (int id = tid; id < 4992; id += 1024)
    ((float4*)Wf)[id] = ((const float4*)WfG)[id];
  if (tid < 200) bias_l[tid] = bih[tid] + bhh[tid];
  if (tid < 8) len_l[tid] = lens[b0 + tid];
  for (int id = tid; id < 512; id += 1024) ((float4*)xs)[id] = make_float4(0.f, 0.f, 0.f, 0.f);
  for (int id = tid; id < 128; id += 1024) ((float4*)hs)[id] = make_float4(0.f, 0.f, 0.f, 0.f);
  __syncthreads();

  int maxlen = 1;
  #pragma unroll
  for (int b = 0; b < 8; b++) maxlen = max(maxlen, len_l[b]);

  int wv = tid >> 6, l = tid & 63;
  int lrow = l & 15, lk = l >> 4;
  bool pvalid = tid >= 824;                    // 200 prefetch threads (waves 12-15)
  int pidx = pvalid ? (tid - 824) : 0;
  int prow = pidx / 25, pkq = pidx % 25;
  int u_ = tid % 50, b_ = tid / 50;            // nonlin mapping (tid<400)

  if (pvalid) {
    float4 xv = *(const float4*)(x + (size_t)(b0 + prow) * (L_ * D_) + pkq * 4);
    half4v h4 = { (_Float16)xv.x, (_Float16)xv.y, (_Float16)xv.z, (_Float16)xv.w };
    *(half4v*)((char*)&xs[0][0] + prow * 256 + (((pkq >> 1) ^ (prow & 7)) << 4) + (pkq & 1) * 8) = h4;
  }
  __syncthreads();

  float cstate = 0.f;
  for (int t = 0; t < maxlen; t++) {
    int cur = t & 1, nxt = cur ^ 1;
    // (a) prefetch t+1
    float4 pf;
    if (pvalid) {
      int tp = min(t + 1, L_ - 1);
      pf = *(const float4*)(x + (size_t)(b0 + prow) * (L_ * D_) + tp * D_ + pkq * 4);
    }
    // (b) MFMA: wave wv -> gate tile wv
    if (wv < 13) {
      half8v ax[4], ah[2];
      #pragma unroll
      for (int ks = 0; ks < 4; ks++)
        ax[ks] = *(const half8v*)((const char*)&xs[cur][0] + lrow * 256 + (((ks * 4 + lk) ^ (lrow & 7)) << 4));
      #pragma unroll
      for (int ks = 0; ks < 2; ks++)
        ah[ks] = *(const half8v*)((const char*)hs + lrow * 128 + (((ks * 4 + lk) ^ (lrow & 7)) << 4));
      f32x4 acc = (f32x4){0.f, 0.f, 0.f, 0.f};
      #pragma unroll
      for (int ks = 0; ks < 4; ks++) {
        half8v bf = *(const half8v*)&Wf[(size_t)((wv * 4 + ks) * 64 + l) * 8];
        acc = __builtin_amdgcn_mfma_f32_16x16x32_f16(ax[ks], bf, acc, 0, 0, 0);
      }
      #pragma unroll
      for (int ks = 0; ks < 2; ks++) {
        half8v bf = *(const half8v*)&Wf[(size_t)(3328 + (wv * 2 + ks) * 64 + l) * 8];
        acc = __builtin_amdgcn_mfma_f32_16x16x32_f16(ah[ks], bf, acc, 0, 0, 0);
      }
      // (c) spill gates for real batches (rows 0..7)
      if (lk < 2) {
        #pragma unroll
        for (int q = 0; q < 4; q++)
          gbuf[(lk * 4 + q) * GSTR + wv * 16 + lrow] = acc[q];
      }
    }
    bar_sync();   // (d) vmcnt NOT drained; pf in flight
    // (e) nonlinearity
    if (tid < 400 && t < len_l[b_]) {
      float gi = gbuf[b_ * GSTR + u_]       + bias_l[u_];
      float gf = gbuf[b_ * GSTR + 50 + u_]  + bias_l[50 + u_];
      float gg = gbuf[b_ * GSTR + 100 + u_] + bias_l[100 + u_];
      float go = gbuf[b_ * GSTR + 150 + u_] + bias_l[150 + u_];
      float cn = sigf(gf) * cstate + sigf(gi) * tanhfast(gg);
      cstate = cn;
      float hv = sigf(go) * tanhfast(cn);
      *(_Float16*)((char*)hs + b_ * 128 + (((u_ >> 3) ^ (b_ & 7)) << 4) + (u_ & 7) * 2) = (_Float16)hv;
      if (t == len_l[b_] - 1) U[(size_t)(b0 + b_) * 100 + u_] = hv;
    }
    // (f) land prefetch into xs[nxt]
    if (pvalid) {
      half4v h4 = { (_Float16)pf.x, (_Float16)pf.y, (_Float16)pf.z, (_Float16)pf.w };
      *(half4v*)((char*)&xs[nxt][0] + prow * 256 + (((pkq >> 1) ^ (prow & 7)) << 4) + (pkq & 1) * 8) = h4;
    }
    bar_sync();   // (g)
  }
}

// ---------------- kernel 3: backward single cell (h0=c0=0 -> W_hh_b unused) ----------------
__global__ __launch_bounds__(256) void k_lstm_bwd(const float* __restrict__ x,
                                                  const int* __restrict__ lens,
                                                  const float* __restrict__ Wih,
                                                  const float* __restrict__ bih,
                                                  const float* __restrict__ bhh,
                                                  float* __restrict__ U) {
  __shared__ float W_l[100][200];
  __shared__ float bias_l[200];
  __shared__ float xs[8][100];
  __shared__ float gb[8][200];
  __shared__ int len_l[8];
  int tid = threadIdx.x;
  int b0 = blockIdx.x * 8;
  for (int id = tid; id < 20000; id += 256) { int j = id / 100, i = id % 100; W_l[i][j] = Wih[id]; }
  if (tid < 200) bias_l[tid] = bih[tid] + bhh[tid];
  if (tid < 8) len_l[tid] = lens[b0 + tid];
  __syncthreads();
  for (int id = tid; id < 800; id += 256) {
    int b = id / 100, i = id % 100;
    int t = len_l[b] - 1;
    xs[b][i] = x[(size_t)(b0 + b) * (L_ * D_) + t * D_ + i];
  }
  __syncthreads();
  int j = tid;
  if (j < 200) {
    float acc[8];
    float bj = bias_l[j];
    #pragma unroll
    for (int b = 0; b < 8; b++) acc[b] = bj;
    #pragma unroll 2
    for (int k = 0; k < 100; k++) {
      float w = W_l[k][j];
      #pragma unroll
      for (int b = 0; b < 8; b++) acc[b] = fmaf(w, xs[b][k], acc[b]);
    }
    #pragma unroll
    for (int b = 0; b < 8; b++) gb[b][j] = acc[b];
  }
  __syncthreads();
  if (tid < 200) {
    int uk = tid % 50, ub = tid / 50;
    #pragma unroll
    for (int s = 0; s < 2; s++) {
      int b = ub + 4 * s;
      float gi = gb[b][uk], gg = gb[b][100 + uk], go = gb[b][150 + uk];
      float cn = sigf(gi) * tanhfast(gg);
      U[(size_t)(b0 + b) * 100 + 50 + uk] = sigf(go) * tanhfast(cn);
    }
  }
}

// ---------------- kernel 4: A = E@W1^T (via W1T, coalesced), norms, Cfrag ------
__global__ __launch_bounds__(128) void k_prep(const float* __restrict__ U,
                                              const int* __restrict__ emo_idx,
                                              const int* __restrict__ cau_idx,
                                              const float* __restrict__ W1T,
                                              float* __restrict__ A,
                                              float* __restrict__ En,
                                              float* __restrict__ Cn,
                                              _Float16* __restrict__ Cfrag) {
  __shared__ float u[100];
  int bid = blockIdx.x;
  int tid = threadIdx.x;
  bool is_e = bid < NE;
  int i = is_e ? bid : bid - NE;
  int row = is_e ? emo_idx[i] : cau_idx[i];
  if (tid < 100) u[tid] = U[row * 100 + tid];
  __syncthreads();
  if (is_e && tid < 100) {
    float acc = 0.f;
    #pragma unroll 4
    for (int k = 0; k < 100; k++) acc = fmaf(u[k], W1T[k * 100 + tid], acc);
    A[i * 100 + tid] = acc;
  }
  if (!is_e && tid < 16) {
    int ct = i >> 4, lrow = i & 15;
    int ks = tid >> 2, seg = tid & 3;
    half8v v;
    #pragma unroll
    for (int e2 = 0; e2 < 8; e2++) {
      int k = tid * 8 + e2;
      v[e2] = (_Float16)((k < 100) ? u[k] : 0.f);
    }
    *(half8v*)(Cfrag + ((size_t)((ct * 4 + ks) * 64 + lrow + 16 * seg)) * 8) = v;
  }
  if (tid < 64) {
    float v = u[tid] * u[tid];
    if (tid < 36) v += u[tid + 64] * u[tid + 64];
    for (int o = 32; o > 0; o >>= 1) v += __shfl_down(v, o);
    if (tid == 0) { if (is_e) En[i] = v; else Cn[i] = v; }
  }
}

// ---------------- kernel 5: pair via fp16 MFMA; B from precomputed frags -------
__global__ __launch_bounds__(256, 4) void k_pair(const float* __restrict__ U,
                                                 const int* __restrict__ emo_idx,
                                                 const float* __restrict__ A,
                                                 const float* __restrict__ En,
                                                 const float* __restrict__ Cn,
                                                 const float* __restrict__ W4f,
                                                 const float* __restrict__ W2f,
                                                 const float* __restrict__ Wd,
                                                 const float* __restrict__ W3b,
                                                 const float* __restrict__ clsw,
                                                 const float* __restrict__ clsb,
                                                 const int* __restrict__ label3,
                                                 const _Float16* __restrict__ Cfrag,
                                                 float* __restrict__ out) {
  __shared__ __align__(16) _Float16 Bbf[1792 * 8];  // 28 KB, frag layout
  __shared__ __align__(16) float E_l[128];          // padded, zeros >=100
  __shared__ float addA[112], wd_l[112];
  __shared__ float Cn_l[1024];
  __shared__ float clsw_l[200];
  __shared__ float clsb_l[2];
  __shared__ int   lbl_l[3];
  __shared__ float En_s;

  int tid = threadIdx.x;
  int e = blockIdx.x;
  int erow = emo_idx[e];

  if (tid < 128) E_l[tid] = (tid < 100) ? U[erow * 100 + tid] : 0.f;
  if (tid < 112) {
    bool v = tid < 100;
    addA[tid] = v ? (A[e * 100 + tid] + W3b[tid]) : 0.f;
    wd_l[tid] = v ? Wd[tid] : 0.f;
  }
  if (tid < 200) clsw_l[tid] = clsw[tid];
  if (tid < 2) clsb_l[tid] = clsb[tid];
  if (tid < 3) lbl_l[tid] = label3[e * 3 + tid];
  if (tid == 0) En_s = En[e];
  {
    float4 cv = ((const float4*)Cn)[tid];
    *(float4*)&Cn_l[tid * 4] = cv;
  }
  __syncthreads();

  // B stage: coalesced frag reads + fma with E (d==100 row = E via W4=1,W2=0)
  for (int id = tid; id < 1792; id += 256) {
    int l = id & 63;
    int kb = ((id >> 6) & 3) * 32 + (l >> 4) * 8;
    float4 wa = ((const float4*)W4f)[id * 2], wb = ((const float4*)W4f)[id * 2 + 1];
    float4 va = ((const float4*)W2f)[id * 2], vb = ((const float4*)W2f)[id * 2 + 1];
    float4 ea = *(const float4*)&E_l[kb],     eb = *(const float4*)&E_l[kb + 4];
    half8v h;
    h[0] = (_Float16)fmaf(wa.x, ea.x, va.x);
    h[1] = (_Float16)fmaf(wa.y, ea.y, va.y);
    h[2] = (_Float16)fmaf(wa.z, ea.z, va.z);
    h[3] = (_Float16)fmaf(wa.w, ea.w, va.w);
    h[4] = (_Float16)fmaf(wb.x, eb.x, vb.x);
    h[5] = (_Float16)fmaf(wb.y, eb.y, vb.y);
    h[6] = (_Float16)fmaf(wb.z, eb.z, vb.z);
    h[7] = (_Float16)fmaf(wb.w, eb.w, vb.w);
    *(half8v*)&Bbf[(size_t)id * 8] = h;
  }
  __syncthreads();

  int wv = tid >> 6, l = tid & 63;
  int lrow = l & 15, lk = l >> 4;
  for (int g = 0; g < 8; g++) {
    int ctb = wv * 16 + g * 2;                // 2 c-tiles per iteration
    f32x4 acc[2][7];
    #pragma unroll
    for (int tt = 0; tt < 2; tt++)
      #pragma unroll
      for (int dt = 0; dt < 7; dt++) acc[tt][dt] = (f32x4){0.f, 0.f, 0.f, 0.f};
    #pragma unroll
    for (int ks = 0; ks < 4; ks++) {
      half8v af0 = *(const half8v*)(Cfrag + ((size_t)((ctb * 4 + ks) * 64 + l)) * 8);
      half8v af1 = *(const half8v*)(Cfrag + ((size_t)(((ctb + 1) * 4 + ks) * 64 + l)) * 8);
      #pragma unroll
      for (int dt = 0; dt < 7; dt++) {
        half8v bf = *(const half8v*)&Bbf[(size_t)((dt * 4 + ks) * 64 + l) * 8];
        acc[0][dt] = __builtin_amdgcn_mfma_f32_16x16x32_f16(af0, bf, acc[0][dt], 0, 0, 0);
        acc[1][dt] = __builtin_amdgcn_mfma_f32_16x16x32_f16(af1, bf, acc[1][dt], 0, 0, 0);
      }
    }
    #pragma unroll
    for (int tt = 0; tt < 2; tt++) {
      int ct = ctb + tt;
      float dist[4];
      #pragma unroll
      for (int r = 0; r < 4; r++) {
        float dotv = __shfl(acc[tt][6][r], (l & 48) + 4, 64);   // lane with d=100
        int c = ct * 16 + lk * 4 + r;
        float d2 = En_s + Cn_l[c] - 2.f * dotv;
        dist[r] = sqrtf(fmaxf(d2, 0.f));
      }
      float l0[4] = {0.f, 0.f, 0.f, 0.f}, l1[4] = {0.f, 0.f, 0.f, 0.f};
      #pragma unroll
      for (int dt = 0; dt < 7; dt++) {
        int d = dt * 16 + lrow;
        float av = addA[d], wdv = wd_l[d];
        bool valid = d < 100;
        float cw0 = valid ? clsw_l[d] : 0.f;
        float cw1 = valid ? clsw_l[100 + d] : 0.f;
        #pragma unroll
        for (int r = 0; r < 4; r++) {
          float z = acc[tt][dt][r] + av + dist[r] * wdv;
          float h = sigf(z);
          l0[r] = fmaf(h, cw0, l0[r]);
          l1[r] = fmaf(h, cw1, l1[r]);
        }
      }
      #pragma unroll
      for (int off = 1; off < 16; off <<= 1) {
        #pragma unroll
        for (int r = 0; r < 4; r++) {
          l0[r] += __shfl_xor(l0[r], off, 64);
          l1[r] += __shfl_xor(l1[r], off, 64);
        }
      }
      if (lrow == 0) {
        #pragma unroll
        for (int r = 0; r < 4; r++) {
          int c = ct * 16 + lk * 4 + r;
          float a0 = l0[r] + clsb_l[0], a1 = l1[r] + clsb_l[1];
          float mx = fmaxf(a0, a1);
          float lse = mx + __logf(__expf(a0 - mx) + __expf(a1 - mx));
          int pair = e * 1024 + c;
          out[pair * 2]     = a0 - lse;
          out[pair * 2 + 1] = a1 - lse;
          out[2 * NP + pair] = (lbl_l[0] == c || lbl_l[1] == c || lbl_l[2] == c) ? 1.f : 0.f;
        }
      }
    }
  }
}

extern "C" void kernel_launch(void* const* d_in, const int* in_sizes, int n_in,
                              void* d_out, int out_size, void* d_ws, size_t ws_size,
                              hipStream_t stream) {
  const float* x     = (const float*)d_in[0];
  const int*   lens  = (const int*)d_in[1];
  const int*   emo   = (const int*)d_in[2];
  const int*   cau   = (const int*)d_in[3];
  const int*   lbl3  = (const int*)d_in[4];
  const float* Wih_f = (const float*)d_in[5];
  const float* Whh_f = (const float*)d_in[6];
  const float* bih_f = (const float*)d_in[7];
  const float* bhh_f = (const float*)d_in[8];
  const float* Wih_b = (const float*)d_in[9];
  // d_in[10] = W_hh_b unused: h0 = 0
  const float* bih_b = (const float*)d_in[11];
  const float* bhh_b = (const float*)d_in[12];
  const float* W3w   = (const float*)d_in[13];
  const float* W3b   = (const float*)d_in[14];
  const float* clsw  = (const float*)d_in[15];
  const float* clsb  = (const float*)d_in[16];
  float* out = (float*)d_out;

  char* ws = (char*)d_ws;
  float*     U       = (float*)ws;               // 819200 B
  int*       emo_idx = (int*)(ws + 819200);      // 4096
  int*       cau_idx = (int*)(ws + 823296);      // 4096
  float*     A       = (float*)(ws + 827392);    // 409600 (aliased by WfG until k_prep)
  _Float16*  WfG     = (_Float16*)(ws + 827392); // 79872, dead after k_lstm_fwd
  float*     En      = (float*)(ws + 1236992);   // 4096
  float*     Cn      = (float*)(ws + 1241088);   // 4096
  _Float16*  Cfrag   = (_Float16*)(ws + 1245184);// 262144
  float*     W4f     = (float*)(ws + 1507328);   // 57344
  float*     W2f     = (float*)(ws + 1564672);   // 57344
  float*     W1T     = (float*)(ws + 1622016);   // 40000
  float*     Wd      = (float*)(ws + 1662016);   // 400  -> end 1662416

  hipLaunchKernelGGL(k_wfrag, dim3(64), dim3(256), 0, stream,
                     Wih_f, Whh_f, W3w, WfG, W4f, W2f, W1T, Wd);
  hipLaunchKernelGGL(k_build_idx, dim3(1), dim3(256), 0, stream, emo, cau, emo_idx, cau_idx);
  hipLaunchKernelGGL(k_lstm_fwd, dim3(256), dim3(1024), 0, stream,
                     x, lens, WfG, bih_f, bhh_f, U);
  hipLaunchKernelGGL(k_lstm_bwd, dim3(256), dim3(256), 0, stream,
                     x, lens, Wih_b, bih_b, bhh_b, U);
  hipLaunchKernelGGL(k_prep, dim3(2048), dim3(128), 0, stream,
                     U, emo_idx, cau_idx, W1T, A, En, Cn, Cfrag);
  hipLaunchKernelGGL(k_pair, dim3(1024), dim3(256), 0, stream,
                     U, emo_idx, A, En, Cn, W4f, W2f, Wd, W3b, clsw, clsb, lbl3, Cfrag, out);
}